// Round 16
// baseline (197.062 us; speedup 1.0000x reference)
//
#include <hip/hip_runtime.h>
#include <hip/hip_bf16.h>

#define BN_INV 0.99999500003749968f  // 1/sqrt(1+1e-5)

typedef __attribute__((ext_vector_type(8))) short bf16x8;
typedef __attribute__((ext_vector_type(4))) float f32x4;
typedef __attribute__((ext_vector_type(8))) unsigned short ushort8;
typedef unsigned short u16;

__device__ inline u16 f2bf(float f) {
  union { float f; unsigned int u; } v;
  v.f = f;
  unsigned int r = v.u + 0x7FFFu + ((v.u >> 16) & 1u);
  return (u16)(r >> 16);
}
__device__ inline float bf2f(u16 u) {
  union { unsigned int u; float f; } v;
  v.u = ((unsigned int)u) << 16;
  return v.f;
}
__device__ inline float asf(unsigned int u) {
  union { unsigned int u; float f; } v; v.u = u; return v.f;
}
__device__ inline void unpack8(bf16x8 v, float* f) {
  union { bf16x8 v; unsigned int w[4]; } u; u.v = v;
#pragma unroll
  for (int q = 0; q < 4; ++q) {
    f[2 * q]     = asf(u.w[q] << 16);
    f[2 * q + 1] = asf(u.w[q] & 0xFFFF0000u);
  }
}

#define GLOAD_LDS16(g, l)                                              \
  __builtin_amdgcn_global_load_lds(                                    \
      (const __attribute__((address_space(1))) unsigned int*)(g),      \
      (__attribute__((address_space(3))) unsigned int*)(l), 16, 0, 0)

// ------ merged ring-zero: blocks [0,32) pad, [32,48) xcat, [48,56) xh -------
__global__ __launch_bounds__(256) void k_zero_ring_all(
    u16* __restrict__ pad, u16* __restrict__ xcat, u16* __restrict__ xhp) {
  int blk = blockIdx.x;
  u16* buf; int PADW, CH, nb, b0;
  if (blk < 32)      { buf = pad;  PADW = 130; CH = 256; nb = 32; b0 = 0; }
  else if (blk < 48) { buf = xcat; PADW = 130; CH = 128; nb = 16; b0 = 32; }
  else               { buf = xhp;  PADW = 66;  CH = 128; nb = 8;  b0 = 48; }
  int nring = 2 * PADW + 2 * (PADW - 2);
  int vecs = CH >> 3;
  int total = 4 * nring * vecs;
  ushort8 z = {0, 0, 0, 0, 0, 0, 0, 0};
  for (int i = (blk - b0) * 256 + threadIdx.x; i < total; i += nb * 256) {
    int v = i % vecs;
    int r = (i / vecs) % nring;
    int b = i / (vecs * nring);
    int y, x;
    if (r < PADW) { y = 0; x = r; }
    else if (r < 2 * PADW) { y = PADW - 1; x = r - PADW; }
    else { int s = r - 2 * PADW; y = 1 + (s >> 1); x = (s & 1) ? (PADW - 1) : 0; }
    *(ushort8*)(buf + ((size_t)(b * PADW + y) * PADW + x) * CH + v * 8) = z;
  }
}

// ------ merged weight repack (wr/we/wo2/w1), OIHW -> bf16 [tap][o][c] -------
__global__ __launch_bounds__(256) void k_repack_all(
    const float* __restrict__ wr, const float* __restrict__ wrg,
    const float* __restrict__ we, const float* __restrict__ weg,
    const float* __restrict__ wo2, const float* __restrict__ wo2g,
    const float* __restrict__ w1, const float* __restrict__ w1g,
    u16* __restrict__ wr_bf, u16* __restrict__ we_bf,
    u16* __restrict__ wo2bf, u16* __restrict__ w1bf) {
  int blk = blockIdx.x;
  const float *w, *g; u16* out; int Cout, Cin, OPAD, TAPS, base;
  if (blk < 576)      { w = wr;  g = wrg;  out = wr_bf; Cout = 128; Cin = 128; OPAD = 128; TAPS = 9; base = 0; }
  else if (blk < 720) { w = we;  g = weg;  out = we_bf; Cout = 25;  Cin = 128; OPAD = 32;  TAPS = 9; base = 576; }
  else if (blk < 784) { w = wo2; g = wo2g; out = wo2bf; Cout = 128; Cin = 128; OPAD = 128; TAPS = 1; base = 720; }
  else                { w = w1;  g = w1g;  out = w1bf;  Cout = 64;  Cin = 128; OPAD = 64;  TAPS = 1; base = 784; }
  int idx = (blk - base) * 256 + threadIdx.x;
  int c = idx % Cin;
  int o = (idx / Cin) % OPAD;
  int tap = idx / (Cin * OPAD);
  float v = 0.f;
  if (o < Cout) v = w[(o * Cin + c) * TAPS + tap] * g[o] * BN_INV;
  out[idx] = f2bf(v);
}

// ------ wo1 weights -> MFMA fragment order [tap][cq][nf][kf][lane][8] -------
__global__ __launch_bounds__(256) void k_repack_wo1frag(
    const float* __restrict__ w, const float* __restrict__ g,
    u16* __restrict__ out) {
  int idx = blockIdx.x * 256 + threadIdx.x;  // 294912
  int e   = idx & 7;
  int l   = (idx >> 3) & 63;
  int kf  = (idx >> 9) & 1;
  int nf  = (idx >> 10) & 7;
  int cq  = (idx >> 13) & 3;
  int tap = idx >> 15;
  int o = nf * 16 + (l & 15);
  int c = cq * 64 + (kf * 4 + (l >> 4)) * 8 + e;
  out[idx] = f2bf(w[(o * 256 + c) * 9 + tap] * g[o] * BN_INV);
}

// ================= tiled implicit-GEMM 3x3 conv, bf16 MFMA (we/wr) =========
template <int PADW, int CIN, int NOUT, int NB, int TILE_M, int EPI, int NTHR,
          int WAVES_N>
__global__ __launch_bounds__(NTHR, 1) void k_conv_mfma(
    const u16* __restrict__ pad, const u16* __restrict__ wb,
    const float* __restrict__ bias, void* __restrict__ outp) {
  constexpr int H = PADW - 2;
  constexpr int NSEG = NOUT / NB;
  constexpr int KQ = CIN / 64;
  constexpr int NSTEPS = 9 * KQ;
  constexpr int NWAVES = NTHR / 64;
  constexpr int WAVES_M = NWAVES / WAVES_N;
  constexpr int WN = NB / WAVES_N;
  constexpr int NF = WN / 16;
  constexpr int WM = TILE_M / WAVES_M;
  constexpr int MF = WM / 16;
  constexpr int GRID = 4 * H * NSEG;
  constexpr int CPX = GRID / 8;
  constexpr int ALOADS = TILE_M * 8;
  constexpr int BLOADS = NB * 8;
  __shared__ alignas(16) u16 As[2][TILE_M * 64];
  __shared__ alignas(16) u16 Bs[2][NB * 64];

  int tid = threadIdx.x, wv = tid >> 6, l = tid & 63;
  int wrw = wv / WAVES_N, wc = wv % WAVES_N;
  int bid0 = blockIdx.x;
  int bid = (bid0 & 7) * CPX + (bid0 >> 3);
  int ns = (NSEG > 1) ? (bid % NSEG) : 0;
  int row = (NSEG > 1) ? (bid / NSEG) : bid;
  int b = row / H, y = row % H;
  const u16* pbat = pad + (size_t)b * PADW * PADW * CIN;

  auto stage = [&](int t, int bufi) {
    int tap = t / KQ;
    int ch0 = (t % KQ) * 64;
    int ky = tap / 3, kx = tap % 3;
    const u16* arow = pbat + ((size_t)(y + ky) * PADW + kx) * CIN + ch0;
#pragma unroll
    for (int j = 0; j < ALOADS / NTHR; ++j) {
      int q = j * NTHR + tid;
      int px = q >> 3;
      int sl = (q & 7) ^ (px & 7);
      GLOAD_LDS16(arow + (size_t)px * CIN + sl * 8,
                  (char*)&As[bufi][0] + (size_t)(j * NTHR + (tid & ~63)) * 16);
    }
    const u16* brow = wb + ((size_t)tap * NOUT + ns * NB) * CIN + ch0;
#pragma unroll
    for (int j = 0; j < BLOADS / NTHR; ++j) {
      int q = j * NTHR + tid;
      int co = q >> 3;
      int sl = (q & 7) ^ (co & 7);
      GLOAD_LDS16(brow + (size_t)co * CIN + sl * 8,
                  (char*)&Bs[bufi][0] + (size_t)(j * NTHR + (tid & ~63)) * 16);
    }
    if constexpr (BLOADS % NTHR) {
      if (tid < BLOADS % NTHR) {
        int q = (BLOADS / NTHR) * NTHR + tid;
        int co = q >> 3;
        int sl = (q & 7) ^ (co & 7);
        GLOAD_LDS16(brow + (size_t)co * CIN + sl * 8,
                    (char*)&Bs[bufi][0] +
                        (size_t)((BLOADS / NTHR) * NTHR + (tid & ~63)) * 16);
      }
    }
  };

  f32x4 acc[MF][NF];
#pragma unroll
  for (int m = 0; m < MF; ++m)
#pragma unroll
    for (int n = 0; n < NF; ++n) acc[m][n] = (f32x4){0.f, 0.f, 0.f, 0.f};

  stage(0, 0);
  for (int t = 0; t < NSTEPS; ++t) {
    __syncthreads();
    if (t + 1 < NSTEPS) stage(t + 1, (t + 1) & 1);
    const u16* Ab = &As[t & 1][0];
    const u16* Bb = &Bs[t & 1][0];
    bf16x8 Bf[2][NF];
#pragma unroll
    for (int kf = 0; kf < 2; ++kf)
#pragma unroll
      for (int n = 0; n < NF; ++n) {
        int co = wc * WN + n * 16 + (l & 15);
        int sl = (kf * 4 + (l >> 4)) ^ (co & 7);
        Bf[kf][n] = *(const bf16x8*)((const char*)Bb + co * 128 + sl * 16);
      }
#pragma unroll
    for (int m = 0; m < MF; ++m) {
      int px = wrw * WM + m * 16 + (l & 15);
      int s0 = (l >> 4) ^ (px & 7);
      int s1 = (4 + (l >> 4)) ^ (px & 7);
      bf16x8 a0 = *(const bf16x8*)((const char*)Ab + px * 128 + s0 * 16);
      bf16x8 a1 = *(const bf16x8*)((const char*)Ab + px * 128 + s1 * 16);
#pragma unroll
      for (int n = 0; n < NF; ++n) {
        acc[m][n] = __builtin_amdgcn_mfma_f32_16x16x32_bf16(a0, Bf[0][n], acc[m][n], 0, 0, 0);
        acc[m][n] = __builtin_amdgcn_mfma_f32_16x16x32_bf16(a1, Bf[1][n], acc[m][n], 0, 0, 0);
      }
    }
  }

  int ncol = l & 15, rq = l >> 4;
  size_t pixb = ((size_t)b * H + y) * H;
  if constexpr (EPI == 0) {
    u16* ob = (u16*)outp;
#pragma unroll
    for (int m = 0; m < MF; ++m) {
      int px0 = wrw * WM + m * 16 + rq * 4;
#pragma unroll
      for (int n = 0; n < NF; ++n) {
        int o = ns * NB + wc * WN + n * 16 + ncol;
        float be = bias[o];
#pragma unroll
        for (int r = 0; r < 4; ++r)
          ob[(pixb + px0 + r) * NOUT + o] = f2bf(fmaxf(acc[m][n][r] + be, 0.f));
      }
    }
  } else {  // EPI==2: we-conv — bias + per-pixel softmax over 25 ch -> fp32
    float* sm = (float*)&As[0][0];
    __syncthreads();
#pragma unroll
    for (int m = 0; m < MF; ++m) {
      int px0 = wrw * WM + m * 16 + rq * 4;
#pragma unroll
      for (int n = 0; n < NF; ++n) {
        int o = wc * WN + n * 16 + ncol;
        float be = (o < 25) ? bias[o] : 0.f;
#pragma unroll
        for (int r = 0; r < 4; ++r)
          sm[(px0 + r) * 33 + o] = acc[m][n][r] + be;
      }
    }
    __syncthreads();
    if (tid < TILE_M) {
      int px = tid;
      float v[25];
      float mx = -1e30f;
#pragma unroll
      for (int i = 0; i < 25; ++i) {
        v[i] = sm[px * 33 + i];
        mx = fmaxf(mx, v[i]);
      }
      float s = 0.f;
#pragma unroll
      for (int i = 0; i < 25; ++i) {
        v[i] = expf(v[i] - mx);
        s += v[i];
      }
      float inv = 1.f / s;
      float* wkp = (float*)outp + (pixb + px) * 25;
#pragma unroll
      for (int i = 0; i < 25; ++i) wkp[i] = v[i] * inv;
    }
  }
}

// ============ wo1 conv: A-window in LDS (8 barriers), B frags via L2 =======
// pad [4][130][130][256] bf16; bfrag [9][4][8][2][64][8] bf16 (bn folded).
// 512 thr = 8 waves 2Mx4N; per-wave M=64 x N=32; grid 512 (XCD swizzled).
__global__ __launch_bounds__(512, 1) void k_wo1_conv(
    const u16* __restrict__ pad, const u16* __restrict__ bfrag,
    const float* __restrict__ bias, u16* __restrict__ y1) {
  __shared__ alignas(16) u16 As[3 * 1056 * 8];  // 3 rows x 132 px x 64 ch
  int tid = threadIdx.x, wv = tid >> 6, l = tid & 63;
  int wrw = wv >> 2, wc = wv & 3;
  int bid0 = blockIdx.x;
  int bid = (bid0 & 7) * 64 + (bid0 >> 3);     // 512 blocks, 64/XCD
  int b = bid >> 7, y = bid & 127;
  const u16* pbat = pad + (size_t)b * 130 * 130 * 256;

  f32x4 acc[4][2];
#pragma unroll
  for (int m = 0; m < 4; ++m)
#pragma unroll
    for (int n = 0; n < 2; ++n) acc[m][n] = (f32x4){0.f, 0.f, 0.f, 0.f};

  for (int cq = 0; cq < 4; ++cq) {
    __syncthreads();  // prior A reads complete before overwrite
    {
      const u16* base = pbat + (size_t)y * 130 * 256 + cq * 64;
#pragma unroll
      for (int j = 0; j < 6; ++j) {
        int q = j * 512 + tid;      // 16B slots 0..3071
        int r = q / 1056;
        int s = q - r * 1056;
        int px = s >> 3;
        int sl = (s & 7) ^ (px & 7);
        GLOAD_LDS16(base + ((size_t)r * 130 + px) * 256 + sl * 8,
                    (char*)As + (size_t)(j * 512 + (tid & ~63)) * 16);
      }
      if (tid < 96) {               // slots 3072..3167
        int q = 3072 + tid;
        int r = q / 1056;
        int s = q - r * 1056;
        int px = s >> 3;
        int sl = (s & 7) ^ (px & 7);
        GLOAD_LDS16(base + ((size_t)r * 130 + px) * 256 + sl * 8,
                    (char*)As + (size_t)(3072 + (tid & ~63)) * 16);
      }
    }
    __syncthreads();  // vmcnt(0) drain: A window ready

#pragma unroll
    for (int tap = 0; tap < 9; ++tap) {
      int ky = tap / 3, kx = tap % 3;
      bf16x8 Bf[2][2];
#pragma unroll
      for (int kf = 0; kf < 2; ++kf)
#pragma unroll
        for (int n = 0; n < 2; ++n) {
          int nf = wc * 2 + n;
          Bf[kf][n] = *(const bf16x8*)(bfrag +
              (((((size_t)tap * 4 + cq) * 8 + nf) * 2 + kf) * 64 + l) * 8);
        }
      const u16* arow = As + (size_t)ky * 1056 * 8;
#pragma unroll
      for (int m = 0; m < 4; ++m) {
        int px = wrw * 64 + m * 16 + (l & 15) + kx;
        int s0 = (l >> 4) ^ (px & 7);
        int s1 = (4 + (l >> 4)) ^ (px & 7);
        bf16x8 a0 = *(const bf16x8*)(arow + ((size_t)px * 8 + s0) * 8);
        bf16x8 a1 = *(const bf16x8*)(arow + ((size_t)px * 8 + s1) * 8);
#pragma unroll
        for (int n = 0; n < 2; ++n) {
          acc[m][n] = __builtin_amdgcn_mfma_f32_16x16x32_bf16(a0, Bf[0][n], acc[m][n], 0, 0, 0);
          acc[m][n] = __builtin_amdgcn_mfma_f32_16x16x32_bf16(a1, Bf[1][n], acc[m][n], 0, 0, 0);
        }
      }
    }
  }

  int ncol = l & 15, rq2 = l >> 4;
  size_t pixb = ((size_t)b * 128 + y) * 128;
#pragma unroll
  for (int m = 0; m < 4; ++m) {
    int px0 = wrw * 64 + m * 16 + rq2 * 4;
#pragma unroll
    for (int n = 0; n < 2; ++n) {
      int o = wc * 32 + n * 16 + ncol;
      float be = bias[o];
#pragma unroll
      for (int r = 0; r < 4; ++r)
        y1[(pixb + px0 + r) * 128 + o] = f2bf(fmaxf(acc[m][n][r] + be, 0.f));
    }
  }
}

// ------ merged input staging; xl part does 64 px/block + 64-slot partials ---
__global__ __launch_bounds__(256) void k_stage_in(
    const float* __restrict__ xh, const float* __restrict__ xl,
    u16* __restrict__ xhp, u16* __restrict__ pad, float* __restrict__ gpart) {
  int blk = blockIdx.x;
  int tid = threadIdx.x;
  if (blk < 1024) {
    int idx = blk * 256 + tid;
    int c0 = (idx & 15) * 8;
    int p = idx >> 4;
    int b = p >> 12, pp = p & 4095;
    int y = pp >> 6, x = pp & 63;
    const float* s = xh + (size_t)p * 128 + c0;
    ushort8 o;
#pragma unroll
    for (int j = 0; j < 8; ++j) o[j] = f2bf(s[j]);
    *(ushort8*)(xhp + ((size_t)(b * 66 + y + 1) * 66 + (x + 1)) * 128 + c0) = o;
    return;
  }
  int blk2 = blk - 1024;
  int c0 = (tid & 15) * 8;
  int pxl = tid >> 4;
  int b = (blk2 * 64) >> 14;
  float facc[8] = {0.f, 0.f, 0.f, 0.f, 0.f, 0.f, 0.f, 0.f};
#pragma unroll
  for (int it = 0; it < 4; ++it) {
    int p = blk2 * 64 + it * 16 + pxl;
    int pp = p & 16383;
    int y = pp >> 7, x = pp & 127;
    const float* s = xl + (size_t)p * 128 + c0;
    ushort8 o;
#pragma unroll
    for (int j = 0; j < 8; ++j) {
      float f = s[j];
      facc[j] += f;
      o[j] = f2bf(f);
    }
    *(ushort8*)(pad + ((size_t)(b * 130 + y + 1) * 130 + (x + 1)) * 256 + 128 + c0) = o;
  }
  __shared__ float red[16][16][9];
#pragma unroll
  for (int j = 0; j < 8; ++j) red[pxl][tid & 15][j] = facc[j];
  __syncthreads();
  if (tid < 128) {
    float sum = 0.f;
#pragma unroll
    for (int q = 0; q < 16; ++q) sum += red[q][tid >> 3][tid & 7];
    atomicAdd(&gpart[(size_t)(blk2 & 63) * 512 + b * 128 + tid], sum);
  }
}

// ------ SE MLP + sigmoid -> per-batch weff bf16 [64][128], bn scale folded --
__global__ __launch_bounds__(128) void k_semlp(
    const float* __restrict__ gpart, const float* __restrict__ wf1,
    const float* __restrict__ bf1, const float* __restrict__ wf2,
    const float* __restrict__ bf2, const float* __restrict__ w2,
    const float* __restrict__ w2g, u16* __restrict__ weffb) {
  int b = blockIdx.x;
  int t = threadIdx.x;  // 128
  __shared__ float m[128], hid[32], sg[128];
  float s0 = 0.f;
  for (int s = 0; s < 64; ++s) s0 += gpart[(size_t)s * 512 + b * 128 + t];
  m[t] = s0 * (1.0f / 16384.0f);
  __syncthreads();
  if (t < 32) {
    float a = 0.f;
    for (int c = 0; c < 128; ++c) a += wf1[t * 128 + c] * m[c];
    hid[t] = fmaxf(a + bf1[t], 0.f);
  }
  __syncthreads();
  {
    float a = 0.f;
    for (int r = 0; r < 32; ++r) a += wf2[t * 32 + r] * hid[r];
    a += bf2[t];
    sg[t] = 1.f / (1.f + expf(-a));
  }
  __syncthreads();
  for (int o = 0; o < 64; ++o) {
    float sc = w2g[o] * BN_INV;
    weffb[((size_t)b * 64 + o) * 128 + t] =
        f2bf((w2[o * 256 + t] * sg[t] + w2[o * 256 + 128 + t]) * sc);
  }
}

// ------ merged 1x1 MFMA: t1 (blk<256) | x2 (blk>=256) -----------------------
__global__ __launch_bounds__(256) void k_t1x2(
    const u16* __restrict__ xhp, const u16* __restrict__ w1b,
    const float* __restrict__ w1bias, float* __restrict__ t1,
    const u16* __restrict__ pad, const u16* __restrict__ weffb,
    const float* __restrict__ x2bias, u16* __restrict__ xcat_pad) {
  int t = threadIdx.x;
  int wv = t >> 6, l = t & 63;
  int kg = l >> 4;
  if (blockIdx.x < 256) {
    int blk = blockIdx.x;
    int b = blk >> 6, y = blk & 63;
    int m0 = wv * 16;
    int xc = m0 + (l & 15);
    const u16* abase = xhp + ((size_t)(b * 66 + y + 1) * 66 + xc + 1) * 128 + kg * 8;
    const u16* bbase = w1b + (size_t)(l & 15) * 128 + kg * 8;
    f32x4 acc[4];
#pragma unroll
    for (int i = 0; i < 4; ++i) acc[i] = (f32x4){0.f, 0.f, 0.f, 0.f};
#pragma unroll
    for (int cc = 0; cc < 4; ++cc) {
      bf16x8 a = *(const bf16x8*)(abase + cc * 32);
#pragma unroll
      for (int nf = 0; nf < 4; ++nf) {
        bf16x8 bfr = *(const bf16x8*)(bbase + nf * 16 * 128 + cc * 32);
        acc[nf] = __builtin_amdgcn_mfma_f32_16x16x32_bf16(a, bfr, acc[nf], 0, 0, 0);
      }
    }
    int prow = m0 + (l >> 4) * 4;
    int ncol = l & 15;
    size_t pixb = ((size_t)b << 12) + ((size_t)y << 6);
#pragma unroll
    for (int nf = 0; nf < 4; ++nf) {
      int o = nf * 16 + ncol;
      float be = w1bias[o];
#pragma unroll
      for (int r = 0; r < 4; ++r)
        t1[(pixb + prow + r) * 64 + o] = fmaxf(acc[nf][r] + be, 0.f);
    }
    return;
  }
  int blk = blockIdx.x - 256;
  int b = blk >> 8, rr = blk & 255;
  int y = rr >> 1;
  int xseg = (rr & 1) << 6;
  int m0 = xseg + wv * 16;
  int xc = m0 + (l & 15);
  const u16* abase =
      pad + ((size_t)(b * 130 + y + 1) * 130 + xc + 1) * 256 + 128 + kg * 8;
  const u16* bbase = weffb + (size_t)b * 64 * 128 + (size_t)(l & 15) * 128 + kg * 8;
  f32x4 acc[4];
#pragma unroll
  for (int i = 0; i < 4; ++i) acc[i] = (f32x4){0.f, 0.f, 0.f, 0.f};
#pragma unroll
  for (int cc = 0; cc < 4; ++cc) {
    bf16x8 a = *(const bf16x8*)(abase + cc * 32);
#pragma unroll
    for (int nf = 0; nf < 4; ++nf) {
      bf16x8 bfr = *(const bf16x8*)(bbase + nf * 16 * 128 + cc * 32);
      acc[nf] = __builtin_amdgcn_mfma_f32_16x16x32_bf16(a, bfr, acc[nf], 0, 0, 0);
    }
  }
  int prow = m0 + (l >> 4) * 4;
  int ncol = l & 15;
  size_t rb = (size_t)(b * 130 + y + 1) * 130;
#pragma unroll
  for (int nf = 0; nf < 4; ++nf) {
    int o = nf * 16 + ncol;
    float be = x2bias[o];
#pragma unroll
    for (int r = 0; r < 4; ++r)
      xcat_pad[(rb + prow + r + 1) * 128 + 64 + o] =
          f2bf(fmaxf(acc[nf][r] + be, 0.f));
  }
}

// ------ bilinear up 64->128 of t1 (64ch) -> xcat_pad bf16 ch 0..63 ----------
__global__ __launch_bounds__(256) void k_up64_pad(const float* __restrict__ in,
                                                  u16* __restrict__ pad) {
  int t = threadIdx.x;
  int cp = (t & 31) * 2;
  int sub = t >> 5;
  int g = blockIdx.x * 8 + sub;
  int b = g >> 14, pp = g & 16383;
  int oy = pp >> 7, ox = pp & 127;
  const float S = 63.0f / 127.0f;
  float fy = oy * S, fx = ox * S;
  int y0 = (int)fy, x0 = (int)fx;
  int y1 = min(y0 + 1, 63), x1 = min(x0 + 1, 63);
  float wy = fy - y0, wx = fx - x0;
  const float* base = in + (size_t)b * 4096 * 64;
  float2 v00 = *(const float2*)(base + ((y0 << 6) + x0) * 64 + cp);
  float2 v01 = *(const float2*)(base + ((y0 << 6) + x1) * 64 + cp);
  float2 v10 = *(const float2*)(base + ((y1 << 6) + x0) * 64 + cp);
  float2 v11 = *(const float2*)(base + ((y1 << 6) + x1) * 64 + cp);
  float r0 = (v00.x * (1.f - wx) + v01.x * wx) * (1.f - wy) +
             (v10.x * (1.f - wx) + v11.x * wx) * wy;
  float r1 = (v00.y * (1.f - wx) + v01.y * wx) * (1.f - wy) +
             (v10.y * (1.f - wx) + v11.y * wx) * wy;
  ushort2 o2; o2.x = f2bf(r0); o2.y = f2bf(r1);
  *(ushort2*)(pad + ((size_t)(b * 130 + oy + 1) * 130 + ox + 1) * 128 + cp) = o2;
}

// ------ bilinear up 64->128 of xr (bf16,128ch) -> xup bf16, 8ch/thread ------
__global__ __launch_bounds__(256) void k_up128_bf(
    const u16* __restrict__ in, u16* __restrict__ outb) {
  int t = threadIdx.x;
  int c0 = (t & 15) * 8;
  int px = t >> 4;
  int g = blockIdx.x * 16 + px;
  int b = g >> 14, pp = g & 16383;
  int oy = pp >> 7, ox = pp & 127;
  const float S = 63.0f / 127.0f;
  float fy = oy * S, fx = ox * S;
  int y0 = (int)fy, x0 = (int)fx;
  int y1 = min(y0 + 1, 63), x1 = min(x0 + 1, 63);
  float wy = fy - y0, wx = fx - x0;
  const u16* base = in + (size_t)b * 4096 * 128 + c0;
  bf16x8 v00 = *(const bf16x8*)(base + ((y0 << 6) + x0) * 128);
  bf16x8 v01 = *(const bf16x8*)(base + ((y0 << 6) + x1) * 128);
  bf16x8 v10 = *(const bf16x8*)(base + ((y1 << 6) + x0) * 128);
  bf16x8 v11 = *(const bf16x8*)(base + ((y1 << 6) + x1) * 128);
  float f00[8], f01[8], f10[8], f11[8];
  unpack8(v00, f00); unpack8(v01, f01); unpack8(v10, f10); unpack8(v11, f11);
  ushort8 o;
#pragma unroll
  for (int j = 0; j < 8; ++j) {
    float top = f00[j] * (1.f - wx) + f01[j] * wx;
    float bot = f10[j] * (1.f - wx) + f11[j] * wx;
    o[j] = f2bf(top * (1.f - wy) + bot * wy);
  }
  *(ushort8*)(outb + (size_t)g * 128 + c0) = o;
}

// ------ CARAFE reassembly (bf16 in) -> wo1-input pad ch 0..127, 8ch/thread --
__global__ __launch_bounds__(256) void k_carafe_bf(
    const u16* __restrict__ xup, const float* __restrict__ wk,
    u16* __restrict__ pad) {
  int t = threadIdx.x;
  int c0 = (t & 15) * 8;
  int px = t >> 4;
  int blk = (blockIdx.x & 7) * 512 + (blockIdx.x >> 3);
  int g = blk * 16 + px;
  int b = g >> 14, pp = g & 16383;
  int y = pp >> 7, x = pp & 127;
  __shared__ float wl[16][26];
  for (int i = t; i < 400; i += 256)
    wl[i / 25][i % 25] = wk[(size_t)(blk * 16 + i / 25) * 25 + (i % 25)];
  __syncthreads();
  float acc[8] = {0.f, 0.f, 0.f, 0.f, 0.f, 0.f, 0.f, 0.f};
  const u16* base = xup + ((size_t)b << 14) * 128 + c0;
#pragma unroll
  for (int i = 0; i < 5; ++i) {
    int row = y + 2 * i - 4;
    if ((unsigned)row >= 128u) continue;
#pragma unroll
    for (int jj = 0; jj < 5; ++jj) {
      int col = x + 2 * jj - 4;
      if ((unsigned)col >= 128u) continue;
      bf16x8 v = *(const bf16x8*)(base + (size_t)((row << 7) + col) * 128);
      float w = wl[px][i * 5 + jj];
      float f[8];
      unpack8(v, f);
#pragma unroll
      for (int k = 0; k < 8; ++k) acc[k] += w * f[k];
    }
  }
  ushort8 o;
#pragma unroll
  for (int k = 0; k < 8; ++k) o[k] = f2bf(acc[k]);
  *(ushort8*)(pad + ((size_t)(b * 130 + y + 1) * 130 + (x + 1)) * 256 + c0) = o;
}

// ------ wo2 1x1 MFMA: y1 bf16 x [128][128] -> out NCHW fp32, relu (LDS epi) -
__global__ __launch_bounds__(256) void k_wo2_mfma(
    const u16* __restrict__ y1, const u16* __restrict__ wb,
    const float* __restrict__ bb, float* __restrict__ out) {
  int t = threadIdx.x;
  int wv = t >> 6, l = t & 63;
  int blk = blockIdx.x;
  int b = blk >> 8, rr = blk & 255;
  int y = rr >> 1;
  int xseg = (rr & 1) << 6;
  int m0 = xseg + wv * 16;
  int xc = m0 + (l & 15);
  int kg = l >> 4;
  const u16* abase =
      y1 + ((size_t)((b << 14) + (y << 7) + xc)) * 128 + kg * 8;
  const u16* bbase = wb + (size_t)(l & 15) * 128 + kg * 8;
  f32x4 acc[8];
#pragma unroll
  for (int i = 0; i < 8; ++i) acc[i] = (f32x4){0.f, 0.f, 0.f, 0.f};
#pragma unroll
  for (int cc = 0; cc < 4; ++cc) {
    bf16x8 a = *(const bf16x8*)(abase + cc * 32);
#pragma unroll
    for (int nf = 0; nf < 8; ++nf) {
      bf16x8 bfr = *(const bf16x8*)(bbase + nf * 16 * 128 + cc * 32);
      acc[nf] = __builtin_amdgcn_mfma_f32_16x16x32_bf16(a, bfr, acc[nf], 0, 0, 0);
    }
  }
  __shared__ float lds[128 * 65];
  int lpx0 = wv * 16 + (l >> 4) * 4;
  int ncol = l & 15;
#pragma unroll
  for (int nf = 0; nf < 8; ++nf) {
    int o = nf * 16 + ncol;
    float be = bb[o];
#pragma unroll
    for (int r = 0; r < 4; ++r)
      lds[o * 65 + lpx0 + r] = fmaxf(acc[nf][r] + be, 0.f);
  }
  __syncthreads();
  size_t obase = (((size_t)(b * 128)) * 128 + y) * 128 + xseg;
#pragma unroll
  for (int rep = 0; rep < 8; ++rep) {
    int idx = rep * 256 + t;
    int o = idx >> 4;
    int x4 = (idx & 15) * 4;
    f32x4 v;
#pragma unroll
    for (int k = 0; k < 4; ++k) v[k] = lds[o * 65 + x4 + k];
    *(f32x4*)(out + obase + (size_t)o * 16384 + x4) = v;
  }
}

extern "C" void kernel_launch(void* const* d_in, const int* in_sizes, int n_in,
                              void* d_out, int out_size, void* d_ws,
                              size_t ws_size, hipStream_t stream) {
  const float* x_h  = (const float*)d_in[0];
  const float* x_l  = (const float*)d_in[1];
  const float* wr   = (const float*)d_in[2];
  const float* wr_g = (const float*)d_in[3];
  const float* wr_b = (const float*)d_in[4];
  const float* w1   = (const float*)d_in[5];
  const float* w1_g = (const float*)d_in[6];
  const float* w1_b = (const float*)d_in[7];
  const float* w2   = (const float*)d_in[8];
  const float* w2_g = (const float*)d_in[9];
  const float* w2_b = (const float*)d_in[10];
  const float* we   = (const float*)d_in[11];
  const float* we_g = (const float*)d_in[12];
  const float* we_b = (const float*)d_in[13];
  const float* wf1  = (const float*)d_in[14];
  const float* bf1  = (const float*)d_in[15];
  const float* wf2  = (const float*)d_in[16];
  const float* bf2  = (const float*)d_in[17];
  const float* wo1  = (const float*)d_in[18];
  const float* wo1_g= (const float*)d_in[19];
  const float* wo1_b= (const float*)d_in[20];
  const float* wo2  = (const float*)d_in[21];
  const float* wo2_g= (const float*)d_in[22];
  const float* wo2_b= (const float*)d_in[23];
  float* out = (float*)d_out;

  float* ws = (float*)d_ws;
  u16* pad      = (u16*)ws;                  // [4][130][130][256] bf16
  u16* xcat_pad = (u16*)(ws + 8652800);      // [4][130][130][128] bf16
  u16* xup      = xcat_pad;                  // reuse after we conv
  float* wkb   = ws + 12979200;              // 1,638,400 f32
  float* t1    = ws + 14617600;              // 1,048,576 f32
  u16* xr = (u16*)t1;                        // reuse after up64
  float* y1reg = ws + 15666176;              // 4,194,304 f32 region
  u16* y1     = (u16*)y1reg;                 // bf16 (late)
  u16* xh_pad = (u16*)y1reg;                 // bf16 (early)
  float* gpart = ws + 19860480;              // 64*512 = 32,768 f32
  u16* weff_bf = (u16*)(gpart + 32768);      // 32,768 bf16
  float* tail  = gpart + 32768 + 16384;
  u16* wr_bf = (u16*)tail;                   // 147,456 bf16
  u16* we_bf = (u16*)(tail + 73728);         // 36,864 bf16
  u16* wo1bf = (u16*)(tail + 73728 + 18432);           // 294,912 bf16 (frag)
  u16* wo2bf = (u16*)(tail + 73728 + 18432 + 147456);  // 16,384 bf16
  u16* w1bf  = (u16*)(tail + 73728 + 18432 + 147456 + 8192);  // 8,192 bf16

  hipMemsetAsync(gpart, 0, 32768 * sizeof(float), stream);
  k_zero_ring_all<<<56, 256, 0, stream>>>(pad, xcat_pad, xh_pad);
  k_repack_all<<<816, 256, 0, stream>>>(wr, wr_g, we, we_g,
                                        wo2, wo2_g, w1, w1_g,
                                        wr_bf, we_bf, wo2bf, w1bf);
  k_repack_wo1frag<<<1152, 256, 0, stream>>>(wo1, wo1_g, wo1bf);

  k_stage_in<<<2048, 256, 0, stream>>>(x_h, x_l, xh_pad, pad, gpart);
  k_semlp<<<4, 128, 0, stream>>>(gpart, wf1, bf1, wf2, bf2, w2, w2_g, weff_bf);
  k_t1x2<<<1280, 256, 0, stream>>>(xh_pad, w1bf, w1_b, t1,
                                   pad, weff_bf, w2_b, xcat_pad);
  k_up64_pad<<<8192, 256, 0, stream>>>(t1, xcat_pad);          // ch 0..63

  // we: 512 thr, 8 waves 4Mx2N (proven config), fused softmax
  k_conv_mfma<130, 128, 32, 32, 128, 2, 512, 2><<<512, 512, 0, stream>>>(
      xcat_pad, we_bf, we_b, wkb);
  // wr: 512 thr, 2Mx4N (proven config)
  k_conv_mfma<66, 128, 128, 64, 64, 0, 512, 4><<<512, 512, 0, stream>>>(
      xh_pad, wr_bf, wr_b, xr);
  k_up128_bf<<<4096, 256, 0, stream>>>(xr, xup);
  k_carafe_bf<<<4096, 256, 0, stream>>>(xup, wkb, pad);
  // wo1: NEW low-barrier structure (A-window LDS + B frags from L2)
  k_wo1_conv<<<512, 512, 0, stream>>>(pad, wo1bf, wo1_b, y1);
  k_wo2_mfma<<<1024, 256, 0, stream>>>(y1, wo2bf, wo2_b, out);
}

// Round 17
// 185.108 us; speedup vs baseline: 1.0646x; 1.0646x over previous
//
#include <hip/hip_runtime.h>
#include <hip/hip_bf16.h>

#define BN_INV 0.99999500003749968f  // 1/sqrt(1+1e-5)

typedef __attribute__((ext_vector_type(8))) short bf16x8;
typedef __attribute__((ext_vector_type(4))) float f32x4;
typedef __attribute__((ext_vector_type(8))) unsigned short ushort8;
typedef unsigned short u16;

__device__ inline u16 f2bf(float f) {
  union { float f; unsigned int u; } v;
  v.f = f;
  unsigned int r = v.u + 0x7FFFu + ((v.u >> 16) & 1u);
  return (u16)(r >> 16);
}
__device__ inline float bf2f(u16 u) {
  union { unsigned int u; float f; } v;
  v.u = ((unsigned int)u) << 16;
  return v.f;
}
__device__ inline float asf(unsigned int u) {
  union { unsigned int u; float f; } v; v.u = u; return v.f;
}
__device__ inline void unpack8(bf16x8 v, float* f) {
  union { bf16x8 v; unsigned int w[4]; } u; u.v = v;
#pragma unroll
  for (int q = 0; q < 4; ++q) {
    f[2 * q]     = asf(u.w[q] << 16);
    f[2 * q + 1] = asf(u.w[q] & 0xFFFF0000u);
  }
}

#define GLOAD_LDS16(g, l)                                              \
  __builtin_amdgcn_global_load_lds(                                    \
      (const __attribute__((address_space(1))) unsigned int*)(g),      \
      (__attribute__((address_space(3))) unsigned int*)(l), 16, 0, 0)

// ------ merged setup: ring-zero (blk<56) + 5-tensor weight repack ----------
__global__ __launch_bounds__(256) void k_setup(
    u16* __restrict__ pad, u16* __restrict__ xcat, u16* __restrict__ xhp,
    const float* __restrict__ wr, const float* __restrict__ wrg,
    const float* __restrict__ we, const float* __restrict__ weg,
    const float* __restrict__ wo1, const float* __restrict__ wo1g,
    const float* __restrict__ wo2, const float* __restrict__ wo2g,
    const float* __restrict__ w1, const float* __restrict__ w1g,
    u16* __restrict__ wr_bf, u16* __restrict__ we_bf, u16* __restrict__ wo1bf,
    u16* __restrict__ wo2bf, u16* __restrict__ w1bf) {
  int blk = blockIdx.x;
  if (blk < 56) {
    u16* buf; int PADW, CH, nb, b0;
    if (blk < 32)      { buf = pad;  PADW = 130; CH = 256; nb = 32; b0 = 0; }
    else if (blk < 48) { buf = xcat; PADW = 130; CH = 128; nb = 16; b0 = 32; }
    else               { buf = xhp;  PADW = 66;  CH = 128; nb = 8;  b0 = 48; }
    int nring = 2 * PADW + 2 * (PADW - 2);
    int vecs = CH >> 3;
    int total = 4 * nring * vecs;
    ushort8 z = {0, 0, 0, 0, 0, 0, 0, 0};
    for (int i = (blk - b0) * 256 + threadIdx.x; i < total; i += nb * 256) {
      int v = i % vecs;
      int r = (i / vecs) % nring;
      int b = i / (vecs * nring);
      int y, x;
      if (r < PADW) { y = 0; x = r; }
      else if (r < 2 * PADW) { y = PADW - 1; x = r - PADW; }
      else { int s = r - 2 * PADW; y = 1 + (s >> 1); x = (s & 1) ? (PADW - 1) : 0; }
      *(ushort8*)(buf + ((size_t)(b * PADW + y) * PADW + x) * CH + v * 8) = z;
    }
    return;
  }
  blk -= 56;  // 0..1967: repack wr/we/wo1/wo2/w1 -> bf16 [tap][o][c]
  const float *w, *g; u16* out; int Cout, Cin, OPAD, TAPS, base;
  if (blk < 576)       { w = wr;  g = wrg;  out = wr_bf; Cout = 128; Cin = 128; OPAD = 128; TAPS = 9; base = 0; }
  else if (blk < 720)  { w = we;  g = weg;  out = we_bf; Cout = 25;  Cin = 128; OPAD = 32;  TAPS = 9; base = 576; }
  else if (blk < 1872) { w = wo1; g = wo1g; out = wo1bf; Cout = 128; Cin = 256; OPAD = 128; TAPS = 9; base = 720; }
  else if (blk < 1936) { w = wo2; g = wo2g; out = wo2bf; Cout = 128; Cin = 128; OPAD = 128; TAPS = 1; base = 1872; }
  else                 { w = w1;  g = w1g;  out = w1bf;  Cout = 64;  Cin = 128; OPAD = 64;  TAPS = 1; base = 1936; }
  int idx = (blk - base) * 256 + threadIdx.x;
  int c = idx % Cin;
  int o = (idx / Cin) % OPAD;
  int tap = idx / (Cin * OPAD);
  float v = 0.f;
  if (o < Cout) v = w[(o * Cin + c) * TAPS + tap] * g[o] * BN_INV;
  out[idx] = f2bf(v);
}

// ================= tiled implicit-GEMM 3x3 conv, bf16 MFMA ==================
// NTHR threads = NTHR/64 waves arranged WAVES_M x WAVES_N; XCD block swizzle.
// EPI 0: bf16 NHWC + bias + relu.  EPI 2: we-conv, fused bias+softmax -> fp32.
// NOTE (R14/R16 post-mortems): this 512-thr 2-phase template is the proven
// point (~30% MfmaUtil structural plateau). 256-thr MF=NF=4 regressed
// (latency-bound); B-frags-from-L2 low-barrier variant also regressed
// (dependent L2 loads inside MFMA loop, occupancy 20%). Keep as-is.
template <int PADW, int CIN, int NOUT, int NB, int TILE_M, int EPI, int NTHR,
          int WAVES_N>
__global__ __launch_bounds__(NTHR, 1) void k_conv_mfma(
    const u16* __restrict__ pad, const u16* __restrict__ wb,
    const float* __restrict__ bias, void* __restrict__ outp) {
  constexpr int H = PADW - 2;
  constexpr int NSEG = NOUT / NB;
  constexpr int KQ = CIN / 64;
  constexpr int NSTEPS = 9 * KQ;
  constexpr int NWAVES = NTHR / 64;
  constexpr int WAVES_M = NWAVES / WAVES_N;
  constexpr int WN = NB / WAVES_N;
  constexpr int NF = WN / 16;
  constexpr int WM = TILE_M / WAVES_M;
  constexpr int MF = WM / 16;
  constexpr int GRID = 4 * H * NSEG;
  constexpr int CPX = GRID / 8;
  constexpr int ALOADS = TILE_M * 8;
  constexpr int BLOADS = NB * 8;
  __shared__ alignas(16) u16 As[2][TILE_M * 64];
  __shared__ alignas(16) u16 Bs[2][NB * 64];

  int tid = threadIdx.x, wv = tid >> 6, l = tid & 63;
  int wrw = wv / WAVES_N, wc = wv % WAVES_N;
  int bid0 = blockIdx.x;
  int bid = (bid0 & 7) * CPX + (bid0 >> 3);
  int ns = (NSEG > 1) ? (bid % NSEG) : 0;
  int row = (NSEG > 1) ? (bid / NSEG) : bid;
  int b = row / H, y = row % H;
  const u16* pbat = pad + (size_t)b * PADW * PADW * CIN;

  auto stage = [&](int t, int bufi) {
    int tap = t / KQ;
    int ch0 = (t % KQ) * 64;
    int ky = tap / 3, kx = tap % 3;
    const u16* arow = pbat + ((size_t)(y + ky) * PADW + kx) * CIN + ch0;
#pragma unroll
    for (int j = 0; j < ALOADS / NTHR; ++j) {
      int q = j * NTHR + tid;
      int px = q >> 3;
      int sl = (q & 7) ^ (px & 7);
      GLOAD_LDS16(arow + (size_t)px * CIN + sl * 8,
                  (char*)&As[bufi][0] + (size_t)(j * NTHR + (tid & ~63)) * 16);
    }
    const u16* brow = wb + ((size_t)tap * NOUT + ns * NB) * CIN + ch0;
#pragma unroll
    for (int j = 0; j < BLOADS / NTHR; ++j) {
      int q = j * NTHR + tid;
      int co = q >> 3;
      int sl = (q & 7) ^ (co & 7);
      GLOAD_LDS16(brow + (size_t)co * CIN + sl * 8,
                  (char*)&Bs[bufi][0] + (size_t)(j * NTHR + (tid & ~63)) * 16);
    }
    if constexpr (BLOADS % NTHR) {
      if (tid < BLOADS % NTHR) {
        int q = (BLOADS / NTHR) * NTHR + tid;
        int co = q >> 3;
        int sl = (q & 7) ^ (co & 7);
        GLOAD_LDS16(brow + (size_t)co * CIN + sl * 8,
                    (char*)&Bs[bufi][0] +
                        (size_t)((BLOADS / NTHR) * NTHR + (tid & ~63)) * 16);
      }
    }
  };

  f32x4 acc[MF][NF];
#pragma unroll
  for (int m = 0; m < MF; ++m)
#pragma unroll
    for (int n = 0; n < NF; ++n) acc[m][n] = (f32x4){0.f, 0.f, 0.f, 0.f};

  stage(0, 0);
  for (int t = 0; t < NSTEPS; ++t) {
    __syncthreads();
    if (t + 1 < NSTEPS) stage(t + 1, (t + 1) & 1);
    const u16* Ab = &As[t & 1][0];
    const u16* Bb = &Bs[t & 1][0];
    bf16x8 Bf[2][NF];
#pragma unroll
    for (int kf = 0; kf < 2; ++kf)
#pragma unroll
      for (int n = 0; n < NF; ++n) {
        int co = wc * WN + n * 16 + (l & 15);
        int sl = (kf * 4 + (l >> 4)) ^ (co & 7);
        Bf[kf][n] = *(const bf16x8*)((const char*)Bb + co * 128 + sl * 16);
      }
#pragma unroll
    for (int m = 0; m < MF; ++m) {
      int px = wrw * WM + m * 16 + (l & 15);
      int s0 = (l >> 4) ^ (px & 7);
      int s1 = (4 + (l >> 4)) ^ (px & 7);
      bf16x8 a0 = *(const bf16x8*)((const char*)Ab + px * 128 + s0 * 16);
      bf16x8 a1 = *(const bf16x8*)((const char*)Ab + px * 128 + s1 * 16);
#pragma unroll
      for (int n = 0; n < NF; ++n) {
        acc[m][n] = __builtin_amdgcn_mfma_f32_16x16x32_bf16(a0, Bf[0][n], acc[m][n], 0, 0, 0);
        acc[m][n] = __builtin_amdgcn_mfma_f32_16x16x32_bf16(a1, Bf[1][n], acc[m][n], 0, 0, 0);
      }
    }
  }

  int ncol = l & 15, rq = l >> 4;
  size_t pixb = ((size_t)b * H + y) * H;
  if constexpr (EPI == 0) {
    u16* ob = (u16*)outp;
#pragma unroll
    for (int m = 0; m < MF; ++m) {
      int px0 = wrw * WM + m * 16 + rq * 4;
#pragma unroll
      for (int n = 0; n < NF; ++n) {
        int o = ns * NB + wc * WN + n * 16 + ncol;
        float be = bias[o];
#pragma unroll
        for (int r = 0; r < 4; ++r)
          ob[(pixb + px0 + r) * NOUT + o] = f2bf(fmaxf(acc[m][n][r] + be, 0.f));
      }
    }
  } else {  // EPI==2: we-conv — bias + per-pixel softmax over 25 ch -> fp32
    float* sm = (float*)&As[0][0];
    __syncthreads();
#pragma unroll
    for (int m = 0; m < MF; ++m) {
      int px0 = wrw * WM + m * 16 + rq * 4;
#pragma unroll
      for (int n = 0; n < NF; ++n) {
        int o = wc * WN + n * 16 + ncol;
        float be = (o < 25) ? bias[o] : 0.f;
#pragma unroll
        for (int r = 0; r < 4; ++r)
          sm[(px0 + r) * 33 + o] = acc[m][n][r] + be;
      }
    }
    __syncthreads();
    if (tid < TILE_M) {
      int px = tid;
      float v[25];
      float mx = -1e30f;
#pragma unroll
      for (int i = 0; i < 25; ++i) {
        v[i] = sm[px * 33 + i];
        mx = fmaxf(mx, v[i]);
      }
      float s = 0.f;
#pragma unroll
      for (int i = 0; i < 25; ++i) {
        v[i] = expf(v[i] - mx);
        s += v[i];
      }
      float inv = 1.f / s;
      float* wkp = (float*)outp + (pixb + px) * 25;
#pragma unroll
      for (int i = 0; i < 25; ++i) wkp[i] = v[i] * inv;
    }
  }
}

// ------ merged input staging; xl part does 64 px/block + 64-slot partials ---
__global__ __launch_bounds__(256) void k_stage_in(
    const float* __restrict__ xh, const float* __restrict__ xl,
    u16* __restrict__ xhp, u16* __restrict__ pad, float* __restrict__ gpart) {
  int blk = blockIdx.x;
  int tid = threadIdx.x;
  if (blk < 1024) {
    int idx = blk * 256 + tid;
    int c0 = (idx & 15) * 8;
    int p = idx >> 4;
    int b = p >> 12, pp = p & 4095;
    int y = pp >> 6, x = pp & 63;
    const float* s = xh + (size_t)p * 128 + c0;
    ushort8 o;
#pragma unroll
    for (int j = 0; j < 8; ++j) o[j] = f2bf(s[j]);
    *(ushort8*)(xhp + ((size_t)(b * 66 + y + 1) * 66 + (x + 1)) * 128 + c0) = o;
    return;
  }
  int blk2 = blk - 1024;
  int c0 = (tid & 15) * 8;
  int pxl = tid >> 4;
  int b = (blk2 * 64) >> 14;
  float facc[8] = {0.f, 0.f, 0.f, 0.f, 0.f, 0.f, 0.f, 0.f};
#pragma unroll
  for (int it = 0; it < 4; ++it) {
    int p = blk2 * 64 + it * 16 + pxl;
    int pp = p & 16383;
    int y = pp >> 7, x = pp & 127;
    const float* s = xl + (size_t)p * 128 + c0;
    ushort8 o;
#pragma unroll
    for (int j = 0; j < 8; ++j) {
      float f = s[j];
      facc[j] += f;
      o[j] = f2bf(f);
    }
    *(ushort8*)(pad + ((size_t)(b * 130 + y + 1) * 130 + (x + 1)) * 256 + 128 + c0) = o;
  }
  __shared__ float red[16][16][9];
#pragma unroll
  for (int j = 0; j < 8; ++j) red[pxl][tid & 15][j] = facc[j];
  __syncthreads();
  if (tid < 128) {
    float sum = 0.f;
#pragma unroll
    for (int q = 0; q < 16; ++q) sum += red[q][tid >> 3][tid & 7];
    atomicAdd(&gpart[(size_t)(blk2 & 63) * 512 + b * 128 + tid], sum);
  }
}

// ------ SE MLP + sigmoid -> per-batch weff bf16 [64][128], bn scale folded --
__global__ __launch_bounds__(128) void k_semlp(
    const float* __restrict__ gpart, const float* __restrict__ wf1,
    const float* __restrict__ bf1, const float* __restrict__ wf2,
    const float* __restrict__ bf2, const float* __restrict__ w2,
    const float* __restrict__ w2g, u16* __restrict__ weffb) {
  int b = blockIdx.x;
  int t = threadIdx.x;  // 128
  __shared__ float m[128], hid[32], sg[128];
  float s0 = 0.f;
  for (int s = 0; s < 64; ++s) s0 += gpart[(size_t)s * 512 + b * 128 + t];
  m[t] = s0 * (1.0f / 16384.0f);
  __syncthreads();
  if (t < 32) {
    float a = 0.f;
    for (int c = 0; c < 128; ++c) a += wf1[t * 128 + c] * m[c];
    hid[t] = fmaxf(a + bf1[t], 0.f);
  }
  __syncthreads();
  {
    float a = 0.f;
    for (int r = 0; r < 32; ++r) a += wf2[t * 32 + r] * hid[r];
    a += bf2[t];
    sg[t] = 1.f / (1.f + expf(-a));
  }
  __syncthreads();
  for (int o = 0; o < 64; ++o) {
    float sc = w2g[o] * BN_INV;
    weffb[((size_t)b * 64 + o) * 128 + t] =
        f2bf((w2[o * 256 + t] * sg[t] + w2[o * 256 + 128 + t]) * sc);
  }
}

// ------ merged 1x1 MFMA: t1 bf16 (blk<256) | x2 (blk>=256) ------------------
__global__ __launch_bounds__(256) void k_t1x2(
    const u16* __restrict__ xhp, const u16* __restrict__ w1b,
    const float* __restrict__ w1bias, u16* __restrict__ t1b,
    const u16* __restrict__ pad, const u16* __restrict__ weffb,
    const float* __restrict__ x2bias, u16* __restrict__ xcat_pad) {
  int t = threadIdx.x;
  int wv = t >> 6, l = t & 63;
  int kg = l >> 4;
  if (blockIdx.x < 256) {
    int blk = blockIdx.x;
    int b = blk >> 6, y = blk & 63;
    int m0 = wv * 16;
    int xc = m0 + (l & 15);
    const u16* abase = xhp + ((size_t)(b * 66 + y + 1) * 66 + xc + 1) * 128 + kg * 8;
    const u16* bbase = w1b + (size_t)(l & 15) * 128 + kg * 8;
    f32x4 acc[4];
#pragma unroll
    for (int i = 0; i < 4; ++i) acc[i] = (f32x4){0.f, 0.f, 0.f, 0.f};
#pragma unroll
    for (int cc = 0; cc < 4; ++cc) {
      bf16x8 a = *(const bf16x8*)(abase + cc * 32);
#pragma unroll
      for (int nf = 0; nf < 4; ++nf) {
        bf16x8 bfr = *(const bf16x8*)(bbase + nf * 16 * 128 + cc * 32);
        acc[nf] = __builtin_amdgcn_mfma_f32_16x16x32_bf16(a, bfr, acc[nf], 0, 0, 0);
      }
    }
    int prow = m0 + (l >> 4) * 4;
    int ncol = l & 15;
    size_t pixb = ((size_t)b << 12) + ((size_t)y << 6);
#pragma unroll
    for (int nf = 0; nf < 4; ++nf) {
      int o = nf * 16 + ncol;
      float be = w1bias[o];
#pragma unroll
      for (int r = 0; r < 4; ++r)
        t1b[(pixb + prow + r) * 64 + o] = f2bf(fmaxf(acc[nf][r] + be, 0.f));
    }
    return;
  }
  int blk = blockIdx.x - 256;
  int b = blk >> 8, rr = blk & 255;
  int y = rr >> 1;
  int xseg = (rr & 1) << 6;
  int m0 = xseg + wv * 16;
  int xc = m0 + (l & 15);
  const u16* abase =
      pad + ((size_t)(b * 130 + y + 1) * 130 + xc + 1) * 256 + 128 + kg * 8;
  const u16* bbase = weffb + (size_t)b * 64 * 128 + (size_t)(l & 15) * 128 + kg * 8;
  f32x4 acc[4];
#pragma unroll
  for (int i = 0; i < 4; ++i) acc[i] = (f32x4){0.f, 0.f, 0.f, 0.f};
#pragma unroll
  for (int cc = 0; cc < 4; ++cc) {
    bf16x8 a = *(const bf16x8*)(abase + cc * 32);
#pragma unroll
    for (int nf = 0; nf < 4; ++nf) {
      bf16x8 bfr = *(const bf16x8*)(bbase + nf * 16 * 128 + cc * 32);
      acc[nf] = __builtin_amdgcn_mfma_f32_16x16x32_bf16(a, bfr, acc[nf], 0, 0, 0);
    }
  }
  int prow = m0 + (l >> 4) * 4;
  int ncol = l & 15;
  size_t rb = (size_t)(b * 130 + y + 1) * 130;
#pragma unroll
  for (int nf = 0; nf < 4; ++nf) {
    int o = nf * 16 + ncol;
    float be = x2bias[o];
#pragma unroll
    for (int r = 0; r < 4; ++r)
      xcat_pad[(rb + prow + r + 1) * 128 + 64 + o] =
          f2bf(fmaxf(acc[nf][r] + be, 0.f));
  }
}

// ------ bilinear up 64->128 of t1 (bf16,64ch) -> xcat_pad ch 0..63, 8ch/thr -
__global__ __launch_bounds__(256) void k_up64_pad(const u16* __restrict__ in,
                                                  u16* __restrict__ pad) {
  int t = threadIdx.x;
  int c0 = (t & 7) * 8;
  int px = t >> 3;                   // 32 px/block
  int g = blockIdx.x * 32 + px;      // B*16384
  int b = g >> 14, pp = g & 16383;
  int oy = pp >> 7, ox = pp & 127;
  const float S = 63.0f / 127.0f;
  float fy = oy * S, fx = ox * S;
  int y0 = (int)fy, x0 = (int)fx;
  int y1 = min(y0 + 1, 63), x1 = min(x0 + 1, 63);
  float wy = fy - y0, wx = fx - x0;
  const u16* base = in + (size_t)b * 4096 * 64 + c0;
  bf16x8 v00 = *(const bf16x8*)(base + ((y0 << 6) + x0) * 64);
  bf16x8 v01 = *(const bf16x8*)(base + ((y0 << 6) + x1) * 64);
  bf16x8 v10 = *(const bf16x8*)(base + ((y1 << 6) + x0) * 64);
  bf16x8 v11 = *(const bf16x8*)(base + ((y1 << 6) + x1) * 64);
  float f00[8], f01[8], f10[8], f11[8];
  unpack8(v00, f00); unpack8(v01, f01); unpack8(v10, f10); unpack8(v11, f11);
  ushort8 o;
#pragma unroll
  for (int j = 0; j < 8; ++j) {
    float top = f00[j] * (1.f - wx) + f01[j] * wx;
    float bot = f10[j] * (1.f - wx) + f11[j] * wx;
    o[j] = f2bf(top * (1.f - wy) + bot * wy);
  }
  *(ushort8*)(pad + ((size_t)(b * 130 + oy + 1) * 130 + ox + 1) * 128 + c0) = o;
}

// ------ bilinear up 64->128 of xr (bf16,128ch) -> xup bf16, 8ch/thread ------
__global__ __launch_bounds__(256) void k_up128_bf(
    const u16* __restrict__ in, u16* __restrict__ outb) {
  int t = threadIdx.x;
  int c0 = (t & 15) * 8;
  int px = t >> 4;
  int g = blockIdx.x * 16 + px;
  int b = g >> 14, pp = g & 16383;
  int oy = pp >> 7, ox = pp & 127;
  const float S = 63.0f / 127.0f;
  float fy = oy * S, fx = ox * S;
  int y0 = (int)fy, x0 = (int)fx;
  int y1 = min(y0 + 1, 63), x1 = min(x0 + 1, 63);
  float wy = fy - y0, wx = fx - x0;
  const u16* base = in + (size_t)b * 4096 * 128 + c0;
  bf16x8 v00 = *(const bf16x8*)(base + ((y0 << 6) + x0) * 128);
  bf16x8 v01 = *(const bf16x8*)(base + ((y0 << 6) + x1) * 128);
  bf16x8 v10 = *(const bf16x8*)(base + ((y1 << 6) + x0) * 128);
  bf16x8 v11 = *(const bf16x8*)(base + ((y1 << 6) + x1) * 128);
  float f00[8], f01[8], f10[8], f11[8];
  unpack8(v00, f00); unpack8(v01, f01); unpack8(v10, f10); unpack8(v11, f11);
  ushort8 o;
#pragma unroll
  for (int j = 0; j < 8; ++j) {
    float top = f00[j] * (1.f - wx) + f01[j] * wx;
    float bot = f10[j] * (1.f - wx) + f11[j] * wx;
    o[j] = f2bf(top * (1.f - wy) + bot * wy);
  }
  *(ushort8*)(outb + (size_t)g * 128 + c0) = o;
}

// ------ CARAFE reassembly (bf16 in) -> wo1-input pad ch 0..127, 8ch/thread --
__global__ __launch_bounds__(256) void k_carafe_bf(
    const u16* __restrict__ xup, const float* __restrict__ wk,
    u16* __restrict__ pad) {
  int t = threadIdx.x;
  int c0 = (t & 15) * 8;
  int px = t >> 4;
  int blk = (blockIdx.x & 7) * 512 + (blockIdx.x >> 3);
  int g = blk * 16 + px;
  int b = g >> 14, pp = g & 16383;
  int y = pp >> 7, x = pp & 127;
  __shared__ float wl[16][26];
  for (int i = t; i < 400; i += 256)
    wl[i / 25][i % 25] = wk[(size_t)(blk * 16 + i / 25) * 25 + (i % 25)];
  __syncthreads();
  float acc[8] = {0.f, 0.f, 0.f, 0.f, 0.f, 0.f, 0.f, 0.f};
  const u16* base = xup + ((size_t)b << 14) * 128 + c0;
#pragma unroll
  for (int i = 0; i < 5; ++i) {
    int row = y + 2 * i - 4;
    if ((unsigned)row >= 128u) continue;
#pragma unroll
    for (int jj = 0; jj < 5; ++jj) {
      int col = x + 2 * jj - 4;
      if ((unsigned)col >= 128u) continue;
      bf16x8 v = *(const bf16x8*)(base + (size_t)((row << 7) + col) * 128);
      float w = wl[px][i * 5 + jj];
      float f[8];
      unpack8(v, f);
#pragma unroll
      for (int k = 0; k < 8; ++k) acc[k] += w * f[k];
    }
  }
  ushort8 o;
#pragma unroll
  for (int k = 0; k < 8; ++k) o[k] = f2bf(acc[k]);
  *(ushort8*)(pad + ((size_t)(b * 130 + y + 1) * 130 + (x + 1)) * 256 + c0) = o;
}

// ------ wo2 1x1 MFMA: y1 bf16 x [128][128] -> out NCHW fp32, relu (LDS epi) -
__global__ __launch_bounds__(256) void k_wo2_mfma(
    const u16* __restrict__ y1, const u16* __restrict__ wb,
    const float* __restrict__ bb, float* __restrict__ out) {
  int t = threadIdx.x;
  int wv = t >> 6, l = t & 63;
  int blk = blockIdx.x;
  int b = blk >> 8, rr = blk & 255;
  int y = rr >> 1;
  int xseg = (rr & 1) << 6;
  int m0 = xseg + wv * 16;
  int xc = m0 + (l & 15);
  int kg = l >> 4;
  const u16* abase =
      y1 + ((size_t)((b << 14) + (y << 7) + xc)) * 128 + kg * 8;
  const u16* bbase = wb + (size_t)(l & 15) * 128 + kg * 8;
  f32x4 acc[8];
#pragma unroll
  for (int i = 0; i < 8; ++i) acc[i] = (f32x4){0.f, 0.f, 0.f, 0.f};
#pragma unroll
  for (int cc = 0; cc < 4; ++cc) {
    bf16x8 a = *(const bf16x8*)(abase + cc * 32);
#pragma unroll
    for (int nf = 0; nf < 8; ++nf) {
      bf16x8 bfr = *(const bf16x8*)(bbase + nf * 16 * 128 + cc * 32);
      acc[nf] = __builtin_amdgcn_mfma_f32_16x16x32_bf16(a, bfr, acc[nf], 0, 0, 0);
    }
  }
  __shared__ float lds[128 * 65];
  int lpx0 = wv * 16 + (l >> 4) * 4;
  int ncol = l & 15;
#pragma unroll
  for (int nf = 0; nf < 8; ++nf) {
    int o = nf * 16 + ncol;
    float be = bb[o];
#pragma unroll
    for (int r = 0; r < 4; ++r)
      lds[o * 65 + lpx0 + r] = fmaxf(acc[nf][r] + be, 0.f);
  }
  __syncthreads();
  size_t obase = (((size_t)(b * 128)) * 128 + y) * 128 + xseg;
#pragma unroll
  for (int rep = 0; rep < 8; ++rep) {
    int idx = rep * 256 + t;
    int o = idx >> 4;
    int x4 = (idx & 15) * 4;
    f32x4 v;
#pragma unroll
    for (int k = 0; k < 4; ++k) v[k] = lds[o * 65 + x4 + k];
    *(f32x4*)(out + obase + (size_t)o * 16384 + x4) = v;
  }
}

extern "C" void kernel_launch(void* const* d_in, const int* in_sizes, int n_in,
                              void* d_out, int out_size, void* d_ws,
                              size_t ws_size, hipStream_t stream) {
  const float* x_h  = (const float*)d_in[0];
  const float* x_l  = (const float*)d_in[1];
  const float* wr   = (const float*)d_in[2];
  const float* wr_g = (const float*)d_in[3];
  const float* wr_b = (const float*)d_in[4];
  const float* w1   = (const float*)d_in[5];
  const float* w1_g = (const float*)d_in[6];
  const float* w1_b = (const float*)d_in[7];
  const float* w2   = (const float*)d_in[8];
  const float* w2_g = (const float*)d_in[9];
  const float* w2_b = (const float*)d_in[10];
  const float* we   = (const float*)d_in[11];
  const float* we_g = (const float*)d_in[12];
  const float* we_b = (const float*)d_in[13];
  const float* wf1  = (const float*)d_in[14];
  const float* bf1  = (const float*)d_in[15];
  const float* wf2  = (const float*)d_in[16];
  const float* bf2  = (const float*)d_in[17];
  const float* wo1  = (const float*)d_in[18];
  const float* wo1_g= (const float*)d_in[19];
  const float* wo1_b= (const float*)d_in[20];
  const float* wo2  = (const float*)d_in[21];
  const float* wo2_g= (const float*)d_in[22];
  const float* wo2_b= (const float*)d_in[23];
  float* out = (float*)d_out;

  float* ws = (float*)d_ws;
  u16* pad      = (u16*)ws;                  // [4][130][130][256] bf16
  u16* xcat_pad = (u16*)(ws + 8652800);      // [4][130][130][128] bf16
  u16* xup      = xcat_pad;                  // reuse after we conv
  float* wkb   = ws + 12979200;              // 1,638,400 f32
  u16* t1b = (u16*)(ws + 14617600);          // 2 MB bf16 (region 4 MB)
  u16* xr  = (u16*)(ws + 14617600);          // reuse after up64
  float* y1reg = ws + 15666176;              // 4,194,304 f32 region
  u16* y1     = (u16*)y1reg;                 // bf16 (late)
  u16* xh_pad = (u16*)y1reg;                 // bf16 (early)
  float* gpart = ws + 19860480;              // 64*512 = 32,768 f32
  u16* weff_bf = (u16*)(gpart + 32768);      // 32,768 bf16
  float* tail  = gpart + 32768 + 16384;
  u16* wr_bf = (u16*)tail;                   // 147,456 bf16
  u16* we_bf = (u16*)(tail + 73728);         // 36,864 bf16
  u16* wo1bf = (u16*)(tail + 73728 + 18432);           // 294,912 bf16
  u16* wo2bf = (u16*)(tail + 73728 + 18432 + 147456);  // 16,384 bf16
  u16* w1bf  = (u16*)(tail + 73728 + 18432 + 147456 + 8192);  // 8,192 bf16

  hipMemsetAsync(gpart, 0, 32768 * sizeof(float), stream);
  k_setup<<<2024, 256, 0, stream>>>(pad, xcat_pad, xh_pad,
                                    wr, wr_g, we, we_g, wo1, wo1_g,
                                    wo2, wo2_g, w1, w1_g,
                                    wr_bf, we_bf, wo1bf, wo2bf, w1bf);

  k_stage_in<<<2048, 256, 0, stream>>>(x_h, x_l, xh_pad, pad, gpart);
  k_semlp<<<4, 128, 0, stream>>>(gpart, wf1, bf1, wf2, bf2, w2, w2_g, weff_bf);
  k_t1x2<<<1280, 256, 0, stream>>>(xh_pad, w1bf, w1_b, t1b,
                                   pad, weff_bf, w2_b, xcat_pad);
  k_up64_pad<<<2048, 256, 0, stream>>>(t1b, xcat_pad);         // ch 0..63

  // we: 512 thr, 8 waves 4Mx2N (proven config), fused softmax
  k_conv_mfma<130, 128, 32, 32, 128, 2, 512, 2><<<512, 512, 0, stream>>>(
      xcat_pad, we_bf, we_b, wkb);
  // wr: 512 thr, 2Mx4N (proven config)
  k_conv_mfma<66, 128, 128, 64, 64, 0, 512, 4><<<512, 512, 0, stream>>>(
      xh_pad, wr_bf, wr_b, xr);
  k_up128_bf<<<4096, 256, 0, stream>>>(xr, xup);
  k_carafe_bf<<<4096, 256, 0, stream>>>(xup, wkb, pad);
  // wo1: 512 thr, 2Mx4N (R13/R15 proven config — R14/R16 alternatives regressed)
  k_conv_mfma<130, 256, 128, 128, 128, 0, 512, 4><<<512, 512, 0, stream>>>(
      pad, wo1bf, wo1_b, y1);
  k_wo2_mfma<<<1024, 256, 0, stream>>>(y1, wo2bf, wo2_b, out);
}

// Round 18
// 176.323 us; speedup vs baseline: 1.1176x; 1.0498x over previous
//
#include <hip/hip_runtime.h>
#include <hip/hip_bf16.h>

#define BN_INV 0.99999500003749968f  // 1/sqrt(1+1e-5)

typedef __attribute__((ext_vector_type(8))) short bf16x8;
typedef __attribute__((ext_vector_type(4))) float f32x4;
typedef __attribute__((ext_vector_type(8))) unsigned short ushort8;
typedef unsigned short u16;

__device__ inline u16 f2bf(float f) {
  union { float f; unsigned int u; } v;
  v.f = f;
  unsigned int r = v.u + 0x7FFFu + ((v.u >> 16) & 1u);
  return (u16)(r >> 16);
}
__device__ inline float bf2f(u16 u) {
  union { unsigned int u; float f; } v;
  v.u = ((unsigned int)u) << 16;
  return v.f;
}
__device__ inline float asf(unsigned int u) {
  union { unsigned int u; float f; } v; v.u = u; return v.f;
}
__device__ inline void unpack8(bf16x8 v, float* f) {
  union { bf16x8 v; unsigned int w[4]; } u; u.v = v;
#pragma unroll
  for (int q = 0; q < 4; ++q) {
    f[2 * q]     = asf(u.w[q] << 16);
    f[2 * q + 1] = asf(u.w[q] & 0xFFFF0000u);
  }
}

#define GLOAD_LDS16(g, l)                                              \
  __builtin_amdgcn_global_load_lds(                                    \
      (const __attribute__((address_space(1))) unsigned int*)(g),      \
      (__attribute__((address_space(3))) unsigned int*)(l), 16, 0, 0)

// ------ merged setup: ring-zero (blk<56) + 5-tensor weight repack ----------
__global__ __launch_bounds__(256) void k_setup(
    u16* __restrict__ pad, u16* __restrict__ xcat, u16* __restrict__ xhp,
    const float* __restrict__ wr, const float* __restrict__ wrg,
    const float* __restrict__ we, const float* __restrict__ weg,
    const float* __restrict__ wo1, const float* __restrict__ wo1g,
    const float* __restrict__ wo2, const float* __restrict__ wo2g,
    const float* __restrict__ w1, const float* __restrict__ w1g,
    u16* __restrict__ wr_bf, u16* __restrict__ we_bf, u16* __restrict__ wo1bf,
    u16* __restrict__ wo2bf, u16* __restrict__ w1bf) {
  int blk = blockIdx.x;
  if (blk < 56) {
    u16* buf; int PADW, CH, nb, b0;
    if (blk < 32)      { buf = pad;  PADW = 130; CH = 256; nb = 32; b0 = 0; }
    else if (blk < 48) { buf = xcat; PADW = 130; CH = 128; nb = 16; b0 = 32; }
    else               { buf = xhp;  PADW = 66;  CH = 128; nb = 8;  b0 = 48; }
    int nring = 2 * PADW + 2 * (PADW - 2);
    int vecs = CH >> 3;
    int total = 4 * nring * vecs;
    ushort8 z = {0, 0, 0, 0, 0, 0, 0, 0};
    for (int i = (blk - b0) * 256 + threadIdx.x; i < total; i += nb * 256) {
      int v = i % vecs;
      int r = (i / vecs) % nring;
      int b = i / (vecs * nring);
      int y, x;
      if (r < PADW) { y = 0; x = r; }
      else if (r < 2 * PADW) { y = PADW - 1; x = r - PADW; }
      else { int s = r - 2 * PADW; y = 1 + (s >> 1); x = (s & 1) ? (PADW - 1) : 0; }
      *(ushort8*)(buf + ((size_t)(b * PADW + y) * PADW + x) * CH + v * 8) = z;
    }
    return;
  }
  blk -= 56;  // 0..1967: repack wr/we/wo1/wo2/w1 -> bf16 [tap][o][c]
  const float *w, *g; u16* out; int Cout, Cin, OPAD, TAPS, base;
  if (blk < 576)       { w = wr;  g = wrg;  out = wr_bf; Cout = 128; Cin = 128; OPAD = 128; TAPS = 9; base = 0; }
  else if (blk < 720)  { w = we;  g = weg;  out = we_bf; Cout = 25;  Cin = 128; OPAD = 32;  TAPS = 9; base = 576; }
  else if (blk < 1872) { w = wo1; g = wo1g; out = wo1bf; Cout = 128; Cin = 256; OPAD = 128; TAPS = 9; base = 720; }
  else if (blk < 1936) { w = wo2; g = wo2g; out = wo2bf; Cout = 128; Cin = 128; OPAD = 128; TAPS = 1; base = 1872; }
  else                 { w = w1;  g = w1g;  out = w1bf;  Cout = 64;  Cin = 128; OPAD = 64;  TAPS = 1; base = 1936; }
  int idx = (blk - base) * 256 + threadIdx.x;
  int c = idx % Cin;
  int o = (idx / Cin) % OPAD;
  int tap = idx / (Cin * OPAD);
  float v = 0.f;
  if (o < Cout) v = w[(o * Cin + c) * TAPS + tap] * g[o] * BN_INV;
  out[idx] = f2bf(v);
}

// ================= tiled implicit-GEMM 3x3 conv, bf16 MFMA (we/wr) =========
// NOTE: 512-thr 2-phase template — proven point (~30% MfmaUtil plateau).
template <int PADW, int CIN, int NOUT, int NB, int TILE_M, int EPI, int NTHR,
          int WAVES_N>
__global__ __launch_bounds__(NTHR, 1) void k_conv_mfma(
    const u16* __restrict__ pad, const u16* __restrict__ wb,
    const float* __restrict__ bias, void* __restrict__ outp) {
  constexpr int H = PADW - 2;
  constexpr int NSEG = NOUT / NB;
  constexpr int KQ = CIN / 64;
  constexpr int NSTEPS = 9 * KQ;
  constexpr int NWAVES = NTHR / 64;
  constexpr int WAVES_M = NWAVES / WAVES_N;
  constexpr int WN = NB / WAVES_N;
  constexpr int NF = WN / 16;
  constexpr int WM = TILE_M / WAVES_M;
  constexpr int MF = WM / 16;
  constexpr int GRID = 4 * H * NSEG;
  constexpr int CPX = GRID / 8;
  constexpr int ALOADS = TILE_M * 8;
  constexpr int BLOADS = NB * 8;
  __shared__ alignas(16) u16 As[2][TILE_M * 64];
  __shared__ alignas(16) u16 Bs[2][NB * 64];

  int tid = threadIdx.x, wv = tid >> 6, l = tid & 63;
  int wrw = wv / WAVES_N, wc = wv % WAVES_N;
  int bid0 = blockIdx.x;
  int bid = (bid0 & 7) * CPX + (bid0 >> 3);
  int ns = (NSEG > 1) ? (bid % NSEG) : 0;
  int row = (NSEG > 1) ? (bid / NSEG) : bid;
  int b = row / H, y = row % H;
  const u16* pbat = pad + (size_t)b * PADW * PADW * CIN;

  auto stage = [&](int t, int bufi) {
    int tap = t / KQ;
    int ch0 = (t % KQ) * 64;
    int ky = tap / 3, kx = tap % 3;
    const u16* arow = pbat + ((size_t)(y + ky) * PADW + kx) * CIN + ch0;
#pragma unroll
    for (int j = 0; j < ALOADS / NTHR; ++j) {
      int q = j * NTHR + tid;
      int px = q >> 3;
      int sl = (q & 7) ^ (px & 7);
      GLOAD_LDS16(arow + (size_t)px * CIN + sl * 8,
                  (char*)&As[bufi][0] + (size_t)(j * NTHR + (tid & ~63)) * 16);
    }
    const u16* brow = wb + ((size_t)tap * NOUT + ns * NB) * CIN + ch0;
#pragma unroll
    for (int j = 0; j < BLOADS / NTHR; ++j) {
      int q = j * NTHR + tid;
      int co = q >> 3;
      int sl = (q & 7) ^ (co & 7);
      GLOAD_LDS16(brow + (size_t)co * CIN + sl * 8,
                  (char*)&Bs[bufi][0] + (size_t)(j * NTHR + (tid & ~63)) * 16);
    }
    if constexpr (BLOADS % NTHR) {
      if (tid < BLOADS % NTHR) {
        int q = (BLOADS / NTHR) * NTHR + tid;
        int co = q >> 3;
        int sl = (q & 7) ^ (co & 7);
        GLOAD_LDS16(brow + (size_t)co * CIN + sl * 8,
                    (char*)&Bs[bufi][0] +
                        (size_t)((BLOADS / NTHR) * NTHR + (tid & ~63)) * 16);
      }
    }
  };

  f32x4 acc[MF][NF];
#pragma unroll
  for (int m = 0; m < MF; ++m)
#pragma unroll
    for (int n = 0; n < NF; ++n) acc[m][n] = (f32x4){0.f, 0.f, 0.f, 0.f};

  stage(0, 0);
  for (int t = 0; t < NSTEPS; ++t) {
    __syncthreads();
    if (t + 1 < NSTEPS) stage(t + 1, (t + 1) & 1);
    const u16* Ab = &As[t & 1][0];
    const u16* Bb = &Bs[t & 1][0];
    bf16x8 Bf[2][NF];
#pragma unroll
    for (int kf = 0; kf < 2; ++kf)
#pragma unroll
      for (int n = 0; n < NF; ++n) {
        int co = wc * WN + n * 16 + (l & 15);
        int sl = (kf * 4 + (l >> 4)) ^ (co & 7);
        Bf[kf][n] = *(const bf16x8*)((const char*)Bb + co * 128 + sl * 16);
      }
#pragma unroll
    for (int m = 0; m < MF; ++m) {
      int px = wrw * WM + m * 16 + (l & 15);
      int s0 = (l >> 4) ^ (px & 7);
      int s1 = (4 + (l >> 4)) ^ (px & 7);
      bf16x8 a0 = *(const bf16x8*)((const char*)Ab + px * 128 + s0 * 16);
      bf16x8 a1 = *(const bf16x8*)((const char*)Ab + px * 128 + s1 * 16);
#pragma unroll
      for (int n = 0; n < NF; ++n) {
        acc[m][n] = __builtin_amdgcn_mfma_f32_16x16x32_bf16(a0, Bf[0][n], acc[m][n], 0, 0, 0);
        acc[m][n] = __builtin_amdgcn_mfma_f32_16x16x32_bf16(a1, Bf[1][n], acc[m][n], 0, 0, 0);
      }
    }
  }

  int ncol = l & 15, rq = l >> 4;
  size_t pixb = ((size_t)b * H + y) * H;
  if constexpr (EPI == 0) {
    u16* ob = (u16*)outp;
#pragma unroll
    for (int m = 0; m < MF; ++m) {
      int px0 = wrw * WM + m * 16 + rq * 4;
#pragma unroll
      for (int n = 0; n < NF; ++n) {
        int o = ns * NB + wc * WN + n * 16 + ncol;
        float be = bias[o];
#pragma unroll
        for (int r = 0; r < 4; ++r)
          ob[(pixb + px0 + r) * NOUT + o] = f2bf(fmaxf(acc[m][n][r] + be, 0.f));
      }
    }
  } else {  // EPI==2: we-conv — bias + per-pixel softmax over 25 ch -> fp32
    float* sm = (float*)&As[0][0];
    __syncthreads();
#pragma unroll
    for (int m = 0; m < MF; ++m) {
      int px0 = wrw * WM + m * 16 + rq * 4;
#pragma unroll
      for (int n = 0; n < NF; ++n) {
        int o = wc * WN + n * 16 + ncol;
        float be = (o < 25) ? bias[o] : 0.f;
#pragma unroll
        for (int r = 0; r < 4; ++r)
          sm[(px0 + r) * 33 + o] = acc[m][n][r] + be;
      }
    }
    __syncthreads();
    if (tid < TILE_M) {
      int px = tid;
      float v[25];
      float mx = -1e30f;
#pragma unroll
      for (int i = 0; i < 25; ++i) {
        v[i] = sm[px * 33 + i];
        mx = fmaxf(mx, v[i]);
      }
      float s = 0.f;
#pragma unroll
      for (int i = 0; i < 25; ++i) {
        v[i] = expf(v[i] - mx);
        s += v[i];
      }
      float inv = 1.f / s;
      float* wkp = (float*)outp + (pixb + px) * 25;
#pragma unroll
      for (int i = 0; i < 25; ++i) wkp[i] = v[i] * inv;
    }
  }
}

// ============ wo1 conv + fused wo2 1x1 (epilogue), 512 thr, 2Mx4N ==========
// Main loop identical to k_conv_mfma<130,256,128,128,128,·,512,4>.
// Epilogue: y1 tile (bf16+relu) -> LDS (swizzled), then per-wave 16px x 128co
// 1x1 MFMA (A from LDS, B frags from L2) -> bias2+relu -> NCHW fp32 stores.
__global__ __launch_bounds__(512, 1) void k_wo1wo2(
    const u16* __restrict__ pad, const u16* __restrict__ wb,
    const float* __restrict__ bias, const u16* __restrict__ w2b,
    const float* __restrict__ bias2, float* __restrict__ out) {
  constexpr int PADW = 130, CIN = 256, NOUT = 128, TILE_M = 128;
  constexpr int H = 128, KQ = 4, NSTEPS = 36;
  constexpr int WN = 32, NF = 2, WM = 64, MF = 4;
  __shared__ alignas(16) u16 smem[32768];  // 64KB: As@0/8192, Bs@16384/24576

  int tid = threadIdx.x, wv = tid >> 6, l = tid & 63;
  int wrw = wv >> 2, wc = wv & 3;
  int bid0 = blockIdx.x;
  int bid = (bid0 & 7) * 64 + (bid0 >> 3);  // XCD swizzle, grid 512
  int b = bid >> 7, y = bid & 127;
  const u16* pbat = pad + (size_t)b * PADW * PADW * CIN;

  auto stage = [&](int t, int bufi) {
    int tap = t / KQ;
    int ch0 = (t % KQ) * 64;
    int ky = tap / 3, kx = tap % 3;
    const u16* arow = pbat + ((size_t)(y + ky) * PADW + kx) * CIN + ch0;
#pragma unroll
    for (int j = 0; j < 2; ++j) {
      int q = j * 512 + tid;
      int px = q >> 3;
      int sl = (q & 7) ^ (px & 7);
      GLOAD_LDS16(arow + (size_t)px * CIN + sl * 8,
                  (char*)smem + (size_t)bufi * 16384 +
                      (size_t)(j * 512 + (tid & ~63)) * 16);
    }
    const u16* brow = wb + (size_t)tap * NOUT * CIN + ch0;
#pragma unroll
    for (int j = 0; j < 2; ++j) {
      int q = j * 512 + tid;
      int co = q >> 3;
      int sl = (q & 7) ^ (co & 7);
      GLOAD_LDS16(brow + (size_t)co * CIN + sl * 8,
                  (char*)smem + 32768 + (size_t)bufi * 16384 +
                      (size_t)(j * 512 + (tid & ~63)) * 16);
    }
  };

  f32x4 acc[MF][NF];
#pragma unroll
  for (int m = 0; m < MF; ++m)
#pragma unroll
    for (int n = 0; n < NF; ++n) acc[m][n] = (f32x4){0.f, 0.f, 0.f, 0.f};

  stage(0, 0);
  for (int t = 0; t < NSTEPS; ++t) {
    __syncthreads();
    if (t + 1 < NSTEPS) stage(t + 1, (t + 1) & 1);
    const u16* Ab = smem + (size_t)(t & 1) * 8192;
    const u16* Bb = smem + 16384 + (size_t)(t & 1) * 8192;
    bf16x8 Bf[2][NF];
#pragma unroll
    for (int kf = 0; kf < 2; ++kf)
#pragma unroll
      for (int n = 0; n < NF; ++n) {
        int co = wc * WN + n * 16 + (l & 15);
        int sl = (kf * 4 + (l >> 4)) ^ (co & 7);
        Bf[kf][n] = *(const bf16x8*)((const char*)Bb + co * 128 + sl * 16);
      }
#pragma unroll
    for (int m = 0; m < MF; ++m) {
      int px = wrw * WM + m * 16 + (l & 15);
      int s0 = (l >> 4) ^ (px & 7);
      int s1 = (4 + (l >> 4)) ^ (px & 7);
      bf16x8 a0 = *(const bf16x8*)((const char*)Ab + px * 128 + s0 * 16);
      bf16x8 a1 = *(const bf16x8*)((const char*)Ab + px * 128 + s1 * 16);
#pragma unroll
      for (int n = 0; n < NF; ++n) {
        acc[m][n] = __builtin_amdgcn_mfma_f32_16x16x32_bf16(a0, Bf[0][n], acc[m][n], 0, 0, 0);
        acc[m][n] = __builtin_amdgcn_mfma_f32_16x16x32_bf16(a1, Bf[1][n], acc[m][n], 0, 0, 0);
      }
    }
  }

  // ---- epilogue: y1 tile -> LDS (bf16, relu, 8-group XOR swizzle) ----
  __syncthreads();  // all LDS reads of main loop done
  u16* y1t = smem;  // [128 px][128 ch], 32KB
  int ncol = l & 15, rq = l >> 4;
#pragma unroll
  for (int m = 0; m < MF; ++m) {
    int px0 = wrw * WM + m * 16 + rq * 4;
#pragma unroll
    for (int n = 0; n < NF; ++n) {
      int ch = wc * WN + n * 16 + ncol;
      float be = bias[ch];
#pragma unroll
      for (int r = 0; r < 4; ++r) {
        int px = px0 + r;
        int g = (ch >> 3) ^ (px & 7);
        y1t[px * 128 + g * 8 + (ch & 7)] =
            f2bf(fmaxf(acc[m][n][r] + be, 0.f));
      }
    }
  }
  __syncthreads();

  // ---- wo2: wave wv owns px wv*16..wv*16+15, all 128 couts ----
  f32x4 acc2[8];
#pragma unroll
  for (int i = 0; i < 8; ++i) acc2[i] = (f32x4){0.f, 0.f, 0.f, 0.f};
  int kg = l >> 4;
  int pxa = wv * 16 + (l & 15);
  const u16* bbase = w2b + (size_t)(l & 15) * 128 + kg * 8;
#pragma unroll
  for (int cc = 0; cc < 4; ++cc) {
    int g = (kg + cc * 4) ^ (pxa & 7);
    bf16x8 a = *(const bf16x8*)(y1t + pxa * 128 + g * 8);
#pragma unroll
    for (int nf = 0; nf < 8; ++nf) {
      bf16x8 bfr = *(const bf16x8*)(bbase + nf * 16 * 128 + cc * 32);
      acc2[nf] = __builtin_amdgcn_mfma_f32_16x16x32_bf16(a, bfr, acc2[nf], 0, 0, 0);
    }
  }
  size_t obase = ((size_t)b * 128) * 16384 + (size_t)y * 128 + wv * 16 + rq * 4;
#pragma unroll
  for (int nf = 0; nf < 8; ++nf) {
    int o = nf * 16 + ncol;
    float be2 = bias2[o];
    f32x4 rv;
#pragma unroll
    for (int k2 = 0; k2 < 4; ++k2) rv[k2] = fmaxf(acc2[nf][k2] + be2, 0.f);
    *(f32x4*)(out + obase + (size_t)o * 16384) = rv;
  }
}

// ------ merged input staging; xl part does 64 px/block + 64-slot partials ---
__global__ __launch_bounds__(256) void k_stage_in(
    const float* __restrict__ xh, const float* __restrict__ xl,
    u16* __restrict__ xhp, u16* __restrict__ pad, float* __restrict__ gpart) {
  int blk = blockIdx.x;
  int tid = threadIdx.x;
  if (blk < 1024) {
    int idx = blk * 256 + tid;
    int c0 = (idx & 15) * 8;
    int p = idx >> 4;
    int b = p >> 12, pp = p & 4095;
    int y = pp >> 6, x = pp & 63;
    const float* s = xh + (size_t)p * 128 + c0;
    ushort8 o;
#pragma unroll
    for (int j = 0; j < 8; ++j) o[j] = f2bf(s[j]);
    *(ushort8*)(xhp + ((size_t)(b * 66 + y + 1) * 66 + (x + 1)) * 128 + c0) = o;
    return;
  }
  int blk2 = blk - 1024;
  int c0 = (tid & 15) * 8;
  int pxl = tid >> 4;
  int b = (blk2 * 64) >> 14;
  float facc[8] = {0.f, 0.f, 0.f, 0.f, 0.f, 0.f, 0.f, 0.f};
#pragma unroll
  for (int it = 0; it < 4; ++it) {
    int p = blk2 * 64 + it * 16 + pxl;
    int pp = p & 16383;
    int y = pp >> 7, x = pp & 127;
    const float* s = xl + (size_t)p * 128 + c0;
    ushort8 o;
#pragma unroll
    for (int j = 0; j < 8; ++j) {
      float f = s[j];
      facc[j] += f;
      o[j] = f2bf(f);
    }
    *(ushort8*)(pad + ((size_t)(b * 130 + y + 1) * 130 + (x + 1)) * 256 + 128 + c0) = o;
  }
  __shared__ float red[16][16][9];
#pragma unroll
  for (int j = 0; j < 8; ++j) red[pxl][tid & 15][j] = facc[j];
  __syncthreads();
  if (tid < 128) {
    float sum = 0.f;
#pragma unroll
    for (int q = 0; q < 16; ++q) sum += red[q][tid >> 3][tid & 7];
    atomicAdd(&gpart[(size_t)(blk2 & 63) * 512 + b * 128 + tid], sum);
  }
}

// ------ SE MLP + sigmoid -> per-batch weff bf16 [64][128], bn scale folded --
__global__ __launch_bounds__(128) void k_semlp(
    const float* __restrict__ gpart, const float* __restrict__ wf1,
    const float* __restrict__ bf1, const float* __restrict__ wf2,
    const float* __restrict__ bf2, const float* __restrict__ w2,
    const float* __restrict__ w2g, u16* __restrict__ weffb) {
  int b = blockIdx.x;
  int t = threadIdx.x;  // 128
  __shared__ float m[128], hid[32], sg[128];
  float s0 = 0.f;
  for (int s = 0; s < 64; ++s) s0 += gpart[(size_t)s * 512 + b * 128 + t];
  m[t] = s0 * (1.0f / 16384.0f);
  __syncthreads();
  if (t < 32) {
    float a = 0.f;
    for (int c = 0; c < 128; ++c) a += wf1[t * 128 + c] * m[c];
    hid[t] = fmaxf(a + bf1[t], 0.f);
  }
  __syncthreads();
  {
    float a = 0.f;
    for (int r = 0; r < 32; ++r) a += wf2[t * 32 + r] * hid[r];
    a += bf2[t];
    sg[t] = 1.f / (1.f + expf(-a));
  }
  __syncthreads();
  for (int o = 0; o < 64; ++o) {
    float sc = w2g[o] * BN_INV;
    weffb[((size_t)b * 64 + o) * 128 + t] =
        f2bf((w2[o * 256 + t] * sg[t] + w2[o * 256 + 128 + t]) * sc);
  }
}

// ------ merged 1x1 MFMA: t1 bf16 (blk<256) | x2 (blk>=256) ------------------
__global__ __launch_bounds__(256) void k_t1x2(
    const u16* __restrict__ xhp, const u16* __restrict__ w1b,
    const float* __restrict__ w1bias, u16* __restrict__ t1b,
    const u16* __restrict__ pad, const u16* __restrict__ weffb,
    const float* __restrict__ x2bias, u16* __restrict__ xcat_pad) {
  int t = threadIdx.x;
  int wv = t >> 6, l = t & 63;
  int kg = l >> 4;
  if (blockIdx.x < 256) {
    int blk = blockIdx.x;
    int b = blk >> 6, y = blk & 63;
    int m0 = wv * 16;
    int xc = m0 + (l & 15);
    const u16* abase = xhp + ((size_t)(b * 66 + y + 1) * 66 + xc + 1) * 128 + kg * 8;
    const u16* bbase = w1b + (size_t)(l & 15) * 128 + kg * 8;
    f32x4 acc[4];
#pragma unroll
    for (int i = 0; i < 4; ++i) acc[i] = (f32x4){0.f, 0.f, 0.f, 0.f};
#pragma unroll
    for (int cc = 0; cc < 4; ++cc) {
      bf16x8 a = *(const bf16x8*)(abase + cc * 32);
#pragma unroll
      for (int nf = 0; nf < 4; ++nf) {
        bf16x8 bfr = *(const bf16x8*)(bbase + nf * 16 * 128 + cc * 32);
        acc[nf] = __builtin_amdgcn_mfma_f32_16x16x32_bf16(a, bfr, acc[nf], 0, 0, 0);
      }
    }
    int prow = m0 + (l >> 4) * 4;
    int ncol = l & 15;
    size_t pixb = ((size_t)b << 12) + ((size_t)y << 6);
#pragma unroll
    for (int nf = 0; nf < 4; ++nf) {
      int o = nf * 16 + ncol;
      float be = w1bias[o];
#pragma unroll
      for (int r = 0; r < 4; ++r)
        t1b[(pixb + prow + r) * 64 + o] = f2bf(fmaxf(acc[nf][r] + be, 0.f));
    }
    return;
  }
  int blk = blockIdx.x - 256;
  int b = blk >> 8, rr = blk & 255;
  int y = rr >> 1;
  int xseg = (rr & 1) << 6;
  int m0 = xseg + wv * 16;
  int xc = m0 + (l & 15);
  const u16* abase =
      pad + ((size_t)(b * 130 + y + 1) * 130 + xc + 1) * 256 + 128 + kg * 8;
  const u16* bbase = weffb + (size_t)b * 64 * 128 + (size_t)(l & 15) * 128 + kg * 8;
  f32x4 acc[4];
#pragma unroll
  for (int i = 0; i < 4; ++i) acc[i] = (f32x4){0.f, 0.f, 0.f, 0.f};
#pragma unroll
  for (int cc = 0; cc < 4; ++cc) {
    bf16x8 a = *(const bf16x8*)(abase + cc * 32);
#pragma unroll
    for (int nf = 0; nf < 4; ++nf) {
      bf16x8 bfr = *(const bf16x8*)(bbase + nf * 16 * 128 + cc * 32);
      acc[nf] = __builtin_amdgcn_mfma_f32_16x16x32_bf16(a, bfr, acc[nf], 0, 0, 0);
    }
  }
  int prow = m0 + (l >> 4) * 4;
  int ncol = l & 15;
  size_t rb = (size_t)(b * 130 + y + 1) * 130;
#pragma unroll
  for (int nf = 0; nf < 4; ++nf) {
    int o = nf * 16 + ncol;
    float be = x2bias[o];
#pragma unroll
    for (int r = 0; r < 4; ++r)
      xcat_pad[(rb + prow + r + 1) * 128 + 64 + o] =
          f2bf(fmaxf(acc[nf][r] + be, 0.f));
  }
}

// ------ bilinear up 64->128 of t1 (bf16,64ch) -> xcat_pad ch 0..63, 8ch/thr -
__global__ __launch_bounds__(256) void k_up64_pad(const u16* __restrict__ in,
                                                  u16* __restrict__ pad) {
  int t = threadIdx.x;
  int c0 = (t & 7) * 8;
  int px = t >> 3;                   // 32 px/block
  int g = blockIdx.x * 32 + px;      // B*16384
  int b = g >> 14, pp = g & 16383;
  int oy = pp >> 7, ox = pp & 127;
  const float S = 63.0f / 127.0f;
  float fy = oy * S, fx = ox * S;
  int y0 = (int)fy, x0 = (int)fx;
  int y1 = min(y0 + 1, 63), x1 = min(x0 + 1, 63);
  float wy = fy - y0, wx = fx - x0;
  const u16* base = in + (size_t)b * 4096 * 64 + c0;
  bf16x8 v00 = *(const bf16x8*)(base + ((y0 << 6) + x0) * 64);
  bf16x8 v01 = *(const bf16x8*)(base + ((y0 << 6) + x1) * 64);
  bf16x8 v10 = *(const bf16x8*)(base + ((y1 << 6) + x0) * 64);
  bf16x8 v11 = *(const bf16x8*)(base + ((y1 << 6) + x1) * 64);
  float f00[8], f01[8], f10[8], f11[8];
  unpack8(v00, f00); unpack8(v01, f01); unpack8(v10, f10); unpack8(v11, f11);
  ushort8 o;
#pragma unroll
  for (int j = 0; j < 8; ++j) {
    float top = f00[j] * (1.f - wx) + f01[j] * wx;
    float bot = f10[j] * (1.f - wx) + f11[j] * wx;
    o[j] = f2bf(top * (1.f - wy) + bot * wy);
  }
  *(ushort8*)(pad + ((size_t)(b * 130 + oy + 1) * 130 + ox + 1) * 128 + c0) = o;
}

// ------ bilinear up 64->128 of xr (bf16,128ch) -> xup bf16, 8ch/thread ------
__global__ __launch_bounds__(256) void k_up128_bf(
    const u16* __restrict__ in, u16* __restrict__ outb) {
  int t = threadIdx.x;
  int c0 = (t & 15) * 8;
  int px = t >> 4;
  int g = blockIdx.x * 16 + px;
  int b = g >> 14, pp = g & 16383;
  int oy = pp >> 7, ox = pp & 127;
  const float S = 63.0f / 127.0f;
  float fy = oy * S, fx = ox * S;
  int y0 = (int)fy, x0 = (int)fx;
  int y1 = min(y0 + 1, 63), x1 = min(x0 + 1, 63);
  float wy = fy - y0, wx = fx - x0;
  const u16* base = in + (size_t)b * 4096 * 128 + c0;
  bf16x8 v00 = *(const bf16x8*)(base + ((y0 << 6) + x0) * 128);
  bf16x8 v01 = *(const bf16x8*)(base + ((y0 << 6) + x1) * 128);
  bf16x8 v10 = *(const bf16x8*)(base + ((y1 << 6) + x0) * 128);
  bf16x8 v11 = *(const bf16x8*)(base + ((y1 << 6) + x1) * 128);
  float f00[8], f01[8], f10[8], f11[8];
  unpack8(v00, f00); unpack8(v01, f01); unpack8(v10, f10); unpack8(v11, f11);
  ushort8 o;
#pragma unroll
  for (int j = 0; j < 8; ++j) {
    float top = f00[j] * (1.f - wx) + f01[j] * wx;
    float bot = f10[j] * (1.f - wx) + f11[j] * wx;
    o[j] = f2bf(top * (1.f - wy) + bot * wy);
  }
  *(ushort8*)(outb + (size_t)g * 128 + c0) = o;
}

// ------ CARAFE reassembly (bf16 in) -> wo1-input pad ch 0..127, 8ch/thread --
__global__ __launch_bounds__(256) void k_carafe_bf(
    const u16* __restrict__ xup, const float* __restrict__ wk,
    u16* __restrict__ pad) {
  int t = threadIdx.x;
  int c0 = (t & 15) * 8;
  int px = t >> 4;
  int blk = (blockIdx.x & 7) * 512 + (blockIdx.x >> 3);
  int g = blk * 16 + px;
  int b = g >> 14, pp = g & 16383;
  int y = pp >> 7, x = pp & 127;
  __shared__ float wl[16][26];
  for (int i = t; i < 400; i += 256)
    wl[i / 25][i % 25] = wk[(size_t)(blk * 16 + i / 25) * 25 + (i % 25)];
  __syncthreads();
  float acc[8] = {0.f, 0.f, 0.f, 0.f, 0.f, 0.f, 0.f, 0.f};
  const u16* base = xup + ((size_t)b << 14) * 128 + c0;
#pragma unroll
  for (int i = 0; i < 5; ++i) {
    int row = y + 2 * i - 4;
    if ((unsigned)row >= 128u) continue;
#pragma unroll
    for (int jj = 0; jj < 5; ++jj) {
      int col = x + 2 * jj - 4;
      if ((unsigned)col >= 128u) continue;
      bf16x8 v = *(const bf16x8*)(base + (size_t)((row << 7) + col) * 128);
      float w = wl[px][i * 5 + jj];
      float f[8];
      unpack8(v, f);
#pragma unroll
      for (int k = 0; k < 8; ++k) acc[k] += w * f[k];
    }
  }
  ushort8 o;
#pragma unroll
  for (int k = 0; k < 8; ++k) o[k] = f2bf(acc[k]);
  *(ushort8*)(pad + ((size_t)(b * 130 + y + 1) * 130 + (x + 1)) * 256 + c0) = o;
}

extern "C" void kernel_launch(void* const* d_in, const int* in_sizes, int n_in,
                              void* d_out, int out_size, void* d_ws,
                              size_t ws_size, hipStream_t stream) {
  const float* x_h  = (const float*)d_in[0];
  const float* x_l  = (const float*)d_in[1];
  const float* wr   = (const float*)d_in[2];
  const float* wr_g = (const float*)d_in[3];
  const float* wr_b = (const float*)d_in[4];
  const float* w1   = (const float*)d_in[5];
  const float* w1_g = (const float*)d_in[6];
  const float* w1_b = (const float*)d_in[7];
  const float* w2   = (const float*)d_in[8];
  const float* w2_g = (const float*)d_in[9];
  const float* w2_b = (const float*)d_in[10];
  const float* we   = (const float*)d_in[11];
  const float* we_g = (const float*)d_in[12];
  const float* we_b = (const float*)d_in[13];
  const float* wf1  = (const float*)d_in[14];
  const float* bf1  = (const float*)d_in[15];
  const float* wf2  = (const float*)d_in[16];
  const float* bf2  = (const float*)d_in[17];
  const float* wo1  = (const float*)d_in[18];
  const float* wo1_g= (const float*)d_in[19];
  const float* wo1_b= (const float*)d_in[20];
  const float* wo2  = (const float*)d_in[21];
  const float* wo2_g= (const float*)d_in[22];
  const float* wo2_b= (const float*)d_in[23];
  float* out = (float*)d_out;

  float* ws = (float*)d_ws;
  u16* pad      = (u16*)ws;                  // [4][130][130][256] bf16
  u16* xcat_pad = (u16*)(ws + 8652800);      // [4][130][130][128] bf16
  u16* xup      = xcat_pad;                  // reuse after we conv
  float* wkb   = ws + 12979200;              // 1,638,400 f32
  u16* t1b = (u16*)(ws + 14617600);          // 2 MB bf16 (region 4 MB)
  u16* xr  = (u16*)(ws + 14617600);          // reuse after up64
  float* y1reg = ws + 15666176;              // 4,194,304 f32 region
  u16* xh_pad = (u16*)y1reg;                 // bf16 (early)
  float* gpart = ws + 19860480;              // 64*512 = 32,768 f32
  u16* weff_bf = (u16*)(gpart + 32768);      // 32,768 bf16
  float* tail  = gpart + 32768 + 16384;
  u16* wr_bf = (u16*)tail;                   // 147,456 bf16
  u16* we_bf = (u16*)(tail + 73728);         // 36,864 bf16
  u16* wo1bf = (u16*)(tail + 73728 + 18432);           // 294,912 bf16
  u16* wo2bf = (u16*)(tail + 73728 + 18432 + 147456);  // 16,384 bf16
  u16* w1bf  = (u16*)(tail + 73728 + 18432 + 147456 + 8192);  // 8,192 bf16

  hipMemsetAsync(gpart, 0, 32768 * sizeof(float), stream);
  k_setup<<<2024, 256, 0, stream>>>(pad, xcat_pad, xh_pad,
                                    wr, wr_g, we, we_g, wo1, wo1_g,
                                    wo2, wo2_g, w1, w1_g,
                                    wr_bf, we_bf, wo1bf, wo2bf, w1bf);

  k_stage_in<<<2048, 256, 0, stream>>>(x_h, x_l, xh_pad, pad, gpart);
  k_semlp<<<4, 128, 0, stream>>>(gpart, wf1, bf1, wf2, bf2, w2, w2_g, weff_bf);
  k_t1x2<<<1280, 256, 0, stream>>>(xh_pad, w1bf, w1_b, t1b,
                                   pad, weff_bf, w2_b, xcat_pad);
  k_up64_pad<<<2048, 256, 0, stream>>>(t1b, xcat_pad);         // ch 0..63

  // we: 512 thr, 8 waves 4Mx2N (proven config), fused softmax
  k_conv_mfma<130, 128, 32, 32, 128, 2, 512, 2><<<512, 512, 0, stream>>>(
      xcat_pad, we_bf, we_b, wkb);
  // wr: 512 thr, 2Mx4N (proven config)
  k_conv_mfma<66, 128, 128, 64, 64, 0, 512, 4><<<512, 512, 0, stream>>>(
      xh_pad, wr_bf, wr_b, xr);
  k_up128_bf<<<4096, 256, 0, stream>>>(xr, xup);
  k_carafe_bf<<<4096, 256, 0, stream>>>(xup, wkb, pad);
  // wo1 + fused wo2 epilogue (R13/R15 proven main loop)
  k_wo1wo2<<<512, 512, 0, stream>>>(pad, wo1bf, wo1_b, wo2bf, wo2_b, out);
}

// Round 19
// 175.871 us; speedup vs baseline: 1.1205x; 1.0026x over previous
//
#include <hip/hip_runtime.h>
#include <hip/hip_bf16.h>

#define BN_INV 0.99999500003749968f  // 1/sqrt(1+1e-5)

typedef __attribute__((ext_vector_type(8))) short bf16x8;
typedef __attribute__((ext_vector_type(4))) float f32x4;
typedef __attribute__((ext_vector_type(8))) unsigned short ushort8;
typedef unsigned short u16;

__device__ inline u16 f2bf(float f) {
  union { float f; unsigned int u; } v;
  v.f = f;
  unsigned int r = v.u + 0x7FFFu + ((v.u >> 16) & 1u);
  return (u16)(r >> 16);
}
__device__ inline float bf2f(u16 u) {
  union { unsigned int u; float f; } v;
  v.u = ((unsigned int)u) << 16;
  return v.f;
}
__device__ inline float asf(unsigned int u) {
  union { unsigned int u; float f; } v; v.u = u; return v.f;
}
__device__ inline void unpack8(bf16x8 v, float* f) {
  union { bf16x8 v; unsigned int w[4]; } u; u.v = v;
#pragma unroll
  for (int q = 0; q < 4; ++q) {
    f[2 * q]     = asf(u.w[q] << 16);
    f[2 * q + 1] = asf(u.w[q] & 0xFFFF0000u);
  }
}

#define GLOAD_LDS16(g, l)                                              \
  __builtin_amdgcn_global_load_lds(                                    \
      (const __attribute__((address_space(1))) unsigned int*)(g),      \
      (__attribute__((address_space(3))) unsigned int*)(l), 16, 0, 0)

// ------ merged setup: ring-zero (blk<56) + 5-tensor weight repack ----------
__global__ __launch_bounds__(256) void k_setup(
    u16* __restrict__ pad, u16* __restrict__ xcat, u16* __restrict__ xhp,
    const float* __restrict__ wr, const float* __restrict__ wrg,
    const float* __restrict__ we, const float* __restrict__ weg,
    const float* __restrict__ wo1, const float* __restrict__ wo1g,
    const float* __restrict__ wo2, const float* __restrict__ wo2g,
    const float* __restrict__ w1, const float* __restrict__ w1g,
    u16* __restrict__ wr_bf, u16* __restrict__ we_bf, u16* __restrict__ wo1bf,
    u16* __restrict__ wo2bf, u16* __restrict__ w1bf) {
  int blk = blockIdx.x;
  if (blk < 56) {
    u16* buf; int PADW, CH, nb, b0;
    if (blk < 32)      { buf = pad;  PADW = 130; CH = 256; nb = 32; b0 = 0; }
    else if (blk < 48) { buf = xcat; PADW = 130; CH = 128; nb = 16; b0 = 32; }
    else               { buf = xhp;  PADW = 66;  CH = 128; nb = 8;  b0 = 48; }
    int nring = 2 * PADW + 2 * (PADW - 2);
    int vecs = CH >> 3;
    int total = 4 * nring * vecs;
    ushort8 z = {0, 0, 0, 0, 0, 0, 0, 0};
    for (int i = (blk - b0) * 256 + threadIdx.x; i < total; i += nb * 256) {
      int v = i % vecs;
      int r = (i / vecs) % nring;
      int b = i / (vecs * nring);
      int y, x;
      if (r < PADW) { y = 0; x = r; }
      else if (r < 2 * PADW) { y = PADW - 1; x = r - PADW; }
      else { int s = r - 2 * PADW; y = 1 + (s >> 1); x = (s & 1) ? (PADW - 1) : 0; }
      *(ushort8*)(buf + ((size_t)(b * PADW + y) * PADW + x) * CH + v * 8) = z;
    }
    return;
  }
  blk -= 56;  // 0..1967: repack wr/we/wo1/wo2/w1 -> bf16 [tap][o][c]
  const float *w, *g; u16* out; int Cout, Cin, OPAD, TAPS, base;
  if (blk < 576)       { w = wr;  g = wrg;  out = wr_bf; Cout = 128; Cin = 128; OPAD = 128; TAPS = 9; base = 0; }
  else if (blk < 720)  { w = we;  g = weg;  out = we_bf; Cout = 25;  Cin = 128; OPAD = 32;  TAPS = 9; base = 576; }
  else if (blk < 1872) { w = wo1; g = wo1g; out = wo1bf; Cout = 128; Cin = 256; OPAD = 128; TAPS = 9; base = 720; }
  else if (blk < 1936) { w = wo2; g = wo2g; out = wo2bf; Cout = 128; Cin = 128; OPAD = 128; TAPS = 1; base = 1872; }
  else                 { w = w1;  g = w1g;  out = w1bf;  Cout = 64;  Cin = 128; OPAD = 64;  TAPS = 1; base = 1936; }
  int idx = (blk - base) * 256 + threadIdx.x;
  int c = idx % Cin;
  int o = (idx / Cin) % OPAD;
  int tap = idx / (Cin * OPAD);
  float v = 0.f;
  if (o < Cout) v = w[(o * Cin + c) * TAPS + tap] * g[o] * BN_INV;
  out[idx] = f2bf(v);
}

// ================= tiled implicit-GEMM 3x3 conv, bf16 MFMA (we/wr) =========
// NOTE: 512-thr 2-phase template — proven point (~30% MfmaUtil plateau).
template <int PADW, int CIN, int NOUT, int NB, int TILE_M, int EPI, int NTHR,
          int WAVES_N>
__global__ __launch_bounds__(NTHR, 1) void k_conv_mfma(
    const u16* __restrict__ pad, const u16* __restrict__ wb,
    const float* __restrict__ bias, void* __restrict__ outp) {
  constexpr int H = PADW - 2;
  constexpr int NSEG = NOUT / NB;
  constexpr int KQ = CIN / 64;
  constexpr int NSTEPS = 9 * KQ;
  constexpr int NWAVES = NTHR / 64;
  constexpr int WAVES_M = NWAVES / WAVES_N;
  constexpr int WN = NB / WAVES_N;
  constexpr int NF = WN / 16;
  constexpr int WM = TILE_M / WAVES_M;
  constexpr int MF = WM / 16;
  constexpr int GRID = 4 * H * NSEG;
  constexpr int CPX = GRID / 8;
  constexpr int ALOADS = TILE_M * 8;
  constexpr int BLOADS = NB * 8;
  __shared__ alignas(16) u16 As[2][TILE_M * 64];
  __shared__ alignas(16) u16 Bs[2][NB * 64];

  int tid = threadIdx.x, wv = tid >> 6, l = tid & 63;
  int wrw = wv / WAVES_N, wc = wv % WAVES_N;
  int bid0 = blockIdx.x;
  int bid = (bid0 & 7) * CPX + (bid0 >> 3);
  int ns = (NSEG > 1) ? (bid % NSEG) : 0;
  int row = (NSEG > 1) ? (bid / NSEG) : bid;
  int b = row / H, y = row % H;
  const u16* pbat = pad + (size_t)b * PADW * PADW * CIN;

  auto stage = [&](int t, int bufi) {
    int tap = t / KQ;
    int ch0 = (t % KQ) * 64;
    int ky = tap / 3, kx = tap % 3;
    const u16* arow = pbat + ((size_t)(y + ky) * PADW + kx) * CIN + ch0;
#pragma unroll
    for (int j = 0; j < ALOADS / NTHR; ++j) {
      int q = j * NTHR + tid;
      int px = q >> 3;
      int sl = (q & 7) ^ (px & 7);
      GLOAD_LDS16(arow + (size_t)px * CIN + sl * 8,
                  (char*)&As[bufi][0] + (size_t)(j * NTHR + (tid & ~63)) * 16);
    }
    const u16* brow = wb + ((size_t)tap * NOUT + ns * NB) * CIN + ch0;
#pragma unroll
    for (int j = 0; j < BLOADS / NTHR; ++j) {
      int q = j * NTHR + tid;
      int co = q >> 3;
      int sl = (q & 7) ^ (co & 7);
      GLOAD_LDS16(brow + (size_t)co * CIN + sl * 8,
                  (char*)&Bs[bufi][0] + (size_t)(j * NTHR + (tid & ~63)) * 16);
    }
    if constexpr (BLOADS % NTHR) {
      if (tid < BLOADS % NTHR) {
        int q = (BLOADS / NTHR) * NTHR + tid;
        int co = q >> 3;
        int sl = (q & 7) ^ (co & 7);
        GLOAD_LDS16(brow + (size_t)co * CIN + sl * 8,
                    (char*)&Bs[bufi][0] +
                        (size_t)((BLOADS / NTHR) * NTHR + (tid & ~63)) * 16);
      }
    }
  };

  f32x4 acc[MF][NF];
#pragma unroll
  for (int m = 0; m < MF; ++m)
#pragma unroll
    for (int n = 0; n < NF; ++n) acc[m][n] = (f32x4){0.f, 0.f, 0.f, 0.f};

  stage(0, 0);
  for (int t = 0; t < NSTEPS; ++t) {
    __syncthreads();
    if (t + 1 < NSTEPS) stage(t + 1, (t + 1) & 1);
    const u16* Ab = &As[t & 1][0];
    const u16* Bb = &Bs[t & 1][0];
    bf16x8 Bf[2][NF];
#pragma unroll
    for (int kf = 0; kf < 2; ++kf)
#pragma unroll
      for (int n = 0; n < NF; ++n) {
        int co = wc * WN + n * 16 + (l & 15);
        int sl = (kf * 4 + (l >> 4)) ^ (co & 7);
        Bf[kf][n] = *(const bf16x8*)((const char*)Bb + co * 128 + sl * 16);
      }
#pragma unroll
    for (int m = 0; m < MF; ++m) {
      int px = wrw * WM + m * 16 + (l & 15);
      int s0 = (l >> 4) ^ (px & 7);
      int s1 = (4 + (l >> 4)) ^ (px & 7);
      bf16x8 a0 = *(const bf16x8*)((const char*)Ab + px * 128 + s0 * 16);
      bf16x8 a1 = *(const bf16x8*)((const char*)Ab + px * 128 + s1 * 16);
#pragma unroll
      for (int n = 0; n < NF; ++n) {
        acc[m][n] = __builtin_amdgcn_mfma_f32_16x16x32_bf16(a0, Bf[0][n], acc[m][n], 0, 0, 0);
        acc[m][n] = __builtin_amdgcn_mfma_f32_16x16x32_bf16(a1, Bf[1][n], acc[m][n], 0, 0, 0);
      }
    }
  }

  int ncol = l & 15, rq = l >> 4;
  size_t pixb = ((size_t)b * H + y) * H;
  if constexpr (EPI == 0) {
    u16* ob = (u16*)outp;
#pragma unroll
    for (int m = 0; m < MF; ++m) {
      int px0 = wrw * WM + m * 16 + rq * 4;
#pragma unroll
      for (int n = 0; n < NF; ++n) {
        int o = ns * NB + wc * WN + n * 16 + ncol;
        float be = bias[o];
#pragma unroll
        for (int r = 0; r < 4; ++r)
          ob[(pixb + px0 + r) * NOUT + o] = f2bf(fmaxf(acc[m][n][r] + be, 0.f));
      }
    }
  } else {  // EPI==2: we-conv — bias + per-pixel softmax over 25 ch -> fp32
    float* sm = (float*)&As[0][0];
    __syncthreads();
#pragma unroll
    for (int m = 0; m < MF; ++m) {
      int px0 = wrw * WM + m * 16 + rq * 4;
#pragma unroll
      for (int n = 0; n < NF; ++n) {
        int o = wc * WN + n * 16 + ncol;
        float be = (o < 25) ? bias[o] : 0.f;
#pragma unroll
        for (int r = 0; r < 4; ++r)
          sm[(px0 + r) * 33 + o] = acc[m][n][r] + be;
      }
    }
    __syncthreads();
    if (tid < TILE_M) {
      int px = tid;
      float v[25];
      float mx = -1e30f;
#pragma unroll
      for (int i = 0; i < 25; ++i) {
        v[i] = sm[px * 33 + i];
        mx = fmaxf(mx, v[i]);
      }
      float s = 0.f;
#pragma unroll
      for (int i = 0; i < 25; ++i) {
        v[i] = expf(v[i] - mx);
        s += v[i];
      }
      float inv = 1.f / s;
      float* wkp = (float*)outp + (pixb + px) * 25;
#pragma unroll
      for (int i = 0; i < 25; ++i) wkp[i] = v[i] * inv;
    }
  }
}

// ============ wo1 conv + fused wo2 1x1 (epilogue), 512 thr, 2Mx4N ==========
// Main loop identical to k_conv_mfma<130,256,128,128,128,·,512,4>.
// Epilogue: y1 tile (bf16+relu) -> LDS (swizzled), then per-wave 16px x 128co
// 1x1 MFMA (A from LDS, B frags from L2) -> bias2+relu -> NCHW fp32 stores.
__global__ __launch_bounds__(512, 1) void k_wo1wo2(
    const u16* __restrict__ pad, const u16* __restrict__ wb,
    const float* __restrict__ bias, const u16* __restrict__ w2b,
    const float* __restrict__ bias2, float* __restrict__ out) {
  constexpr int PADW = 130, CIN = 256, NOUT = 128, TILE_M = 128;
  constexpr int H = 128, KQ = 4, NSTEPS = 36;
  constexpr int WN = 32, NF = 2, WM = 64, MF = 4;
  __shared__ alignas(16) u16 smem[32768];  // 64KB: As@0/8192, Bs@16384/24576

  int tid = threadIdx.x, wv = tid >> 6, l = tid & 63;
  int wrw = wv >> 2, wc = wv & 3;
  int bid0 = blockIdx.x;
  int bid = (bid0 & 7) * 64 + (bid0 >> 3);  // XCD swizzle, grid 512
  int b = bid >> 7, y = bid & 127;
  const u16* pbat = pad + (size_t)b * PADW * PADW * CIN;

  auto stage = [&](int t, int bufi) {
    int tap = t / KQ;
    int ch0 = (t % KQ) * 64;
    int ky = tap / 3, kx = tap % 3;
    const u16* arow = pbat + ((size_t)(y + ky) * PADW + kx) * CIN + ch0;
#pragma unroll
    for (int j = 0; j < 2; ++j) {
      int q = j * 512 + tid;
      int px = q >> 3;
      int sl = (q & 7) ^ (px & 7);
      GLOAD_LDS16(arow + (size_t)px * CIN + sl * 8,
                  (char*)smem + (size_t)bufi * 16384 +
                      (size_t)(j * 512 + (tid & ~63)) * 16);
    }
    const u16* brow = wb + (size_t)tap * NOUT * CIN + ch0;
#pragma unroll
    for (int j = 0; j < 2; ++j) {
      int q = j * 512 + tid;
      int co = q >> 3;
      int sl = (q & 7) ^ (co & 7);
      GLOAD_LDS16(brow + (size_t)co * CIN + sl * 8,
                  (char*)smem + 32768 + (size_t)bufi * 16384 +
                      (size_t)(j * 512 + (tid & ~63)) * 16);
    }
  };

  f32x4 acc[MF][NF];
#pragma unroll
  for (int m = 0; m < MF; ++m)
#pragma unroll
    for (int n = 0; n < NF; ++n) acc[m][n] = (f32x4){0.f, 0.f, 0.f, 0.f};

  stage(0, 0);
  for (int t = 0; t < NSTEPS; ++t) {
    __syncthreads();
    if (t + 1 < NSTEPS) stage(t + 1, (t + 1) & 1);
    const u16* Ab = smem + (size_t)(t & 1) * 8192;
    const u16* Bb = smem + 16384 + (size_t)(t & 1) * 8192;
    bf16x8 Bf[2][NF];
#pragma unroll
    for (int kf = 0; kf < 2; ++kf)
#pragma unroll
      for (int n = 0; n < NF; ++n) {
        int co = wc * WN + n * 16 + (l & 15);
        int sl = (kf * 4 + (l >> 4)) ^ (co & 7);
        Bf[kf][n] = *(const bf16x8*)((const char*)Bb + co * 128 + sl * 16);
      }
#pragma unroll
    for (int m = 0; m < MF; ++m) {
      int px = wrw * WM + m * 16 + (l & 15);
      int s0 = (l >> 4) ^ (px & 7);
      int s1 = (4 + (l >> 4)) ^ (px & 7);
      bf16x8 a0 = *(const bf16x8*)((const char*)Ab + px * 128 + s0 * 16);
      bf16x8 a1 = *(const bf16x8*)((const char*)Ab + px * 128 + s1 * 16);
#pragma unroll
      for (int n = 0; n < NF; ++n) {
        acc[m][n] = __builtin_amdgcn_mfma_f32_16x16x32_bf16(a0, Bf[0][n], acc[m][n], 0, 0, 0);
        acc[m][n] = __builtin_amdgcn_mfma_f32_16x16x32_bf16(a1, Bf[1][n], acc[m][n], 0, 0, 0);
      }
    }
  }

  // ---- epilogue: y1 tile -> LDS (bf16, relu, 8-group XOR swizzle) ----
  __syncthreads();  // all LDS reads of main loop done
  u16* y1t = smem;  // [128 px][128 ch], 32KB
  int ncol = l & 15, rq = l >> 4;
#pragma unroll
  for (int m = 0; m < MF; ++m) {
    int px0 = wrw * WM + m * 16 + rq * 4;
#pragma unroll
    for (int n = 0; n < NF; ++n) {
      int ch = wc * WN + n * 16 + ncol;
      float be = bias[ch];
#pragma unroll
      for (int r = 0; r < 4; ++r) {
        int px = px0 + r;
        int g = (ch >> 3) ^ (px & 7);
        y1t[px * 128 + g * 8 + (ch & 7)] =
            f2bf(fmaxf(acc[m][n][r] + be, 0.f));
      }
    }
  }
  __syncthreads();

  // ---- wo2: wave wv owns px wv*16..wv*16+15, all 128 couts ----
  f32x4 acc2[8];
#pragma unroll
  for (int i = 0; i < 8; ++i) acc2[i] = (f32x4){0.f, 0.f, 0.f, 0.f};
  int kg = l >> 4;
  int pxa = wv * 16 + (l & 15);
  const u16* bbase = w2b + (size_t)(l & 15) * 128 + kg * 8;
#pragma unroll
  for (int cc = 0; cc < 4; ++cc) {
    int g = (kg + cc * 4) ^ (pxa & 7);
    bf16x8 a = *(const bf16x8*)(y1t + pxa * 128 + g * 8);
#pragma unroll
    for (int nf = 0; nf < 8; ++nf) {
      bf16x8 bfr = *(const bf16x8*)(bbase + nf * 16 * 128 + cc * 32);
      acc2[nf] = __builtin_amdgcn_mfma_f32_16x16x32_bf16(a, bfr, acc2[nf], 0, 0, 0);
    }
  }
  size_t obase = ((size_t)b * 128) * 16384 + (size_t)y * 128 + wv * 16 + rq * 4;
#pragma unroll
  for (int nf = 0; nf < 8; ++nf) {
    int o = nf * 16 + ncol;
    float be2 = bias2[o];
    f32x4 rv;
#pragma unroll
    for (int k2 = 0; k2 < 4; ++k2) rv[k2] = fmaxf(acc2[nf][k2] + be2, 0.f);
    *(f32x4*)(out + obase + (size_t)o * 16384) = rv;
  }
}

// ------ merged input staging; xl part does 64 px/block + 64-slot partials ---
__global__ __launch_bounds__(256) void k_stage_in(
    const float* __restrict__ xh, const float* __restrict__ xl,
    u16* __restrict__ xhp, u16* __restrict__ pad, float* __restrict__ gpart) {
  int blk = blockIdx.x;
  int tid = threadIdx.x;
  if (blk < 1024) {
    int idx = blk * 256 + tid;
    int c0 = (idx & 15) * 8;
    int p = idx >> 4;
    int b = p >> 12, pp = p & 4095;
    int y = pp >> 6, x = pp & 63;
    const float* s = xh + (size_t)p * 128 + c0;
    ushort8 o;
#pragma unroll
    for (int j = 0; j < 8; ++j) o[j] = f2bf(s[j]);
    *(ushort8*)(xhp + ((size_t)(b * 66 + y + 1) * 66 + (x + 1)) * 128 + c0) = o;
    return;
  }
  int blk2 = blk - 1024;
  int c0 = (tid & 15) * 8;
  int pxl = tid >> 4;
  int b = (blk2 * 64) >> 14;
  float facc[8] = {0.f, 0.f, 0.f, 0.f, 0.f, 0.f, 0.f, 0.f};
#pragma unroll
  for (int it = 0; it < 4; ++it) {
    int p = blk2 * 64 + it * 16 + pxl;
    int pp = p & 16383;
    int y = pp >> 7, x = pp & 127;
    const float* s = xl + (size_t)p * 128 + c0;
    ushort8 o;
#pragma unroll
    for (int j = 0; j < 8; ++j) {
      float f = s[j];
      facc[j] += f;
      o[j] = f2bf(f);
    }
    *(ushort8*)(pad + ((size_t)(b * 130 + y + 1) * 130 + (x + 1)) * 256 + 128 + c0) = o;
  }
  __shared__ float red[16][16][9];
#pragma unroll
  for (int j = 0; j < 8; ++j) red[pxl][tid & 15][j] = facc[j];
  __syncthreads();
  if (tid < 128) {
    float sum = 0.f;
#pragma unroll
    for (int q = 0; q < 16; ++q) sum += red[q][tid >> 3][tid & 7];
    atomicAdd(&gpart[(size_t)(blk2 & 63) * 512 + b * 128 + tid], sum);
  }
}

// ------ SE MLP + sigmoid -> per-batch weff bf16 [64][128], bn scale folded --
__global__ __launch_bounds__(128) void k_semlp(
    const float* __restrict__ gpart, const float* __restrict__ wf1,
    const float* __restrict__ bf1, const float* __restrict__ wf2,
    const float* __restrict__ bf2, const float* __restrict__ w2,
    const float* __restrict__ w2g, u16* __restrict__ weffb) {
  int b = blockIdx.x;
  int t = threadIdx.x;  // 128
  __shared__ float m[128], hid[32], sg[128];
  float s0 = 0.f;
  for (int s = 0; s < 64; ++s) s0 += gpart[(size_t)s * 512 + b * 128 + t];
  m[t] = s0 * (1.0f / 16384.0f);
  __syncthreads();
  if (t < 32) {
    float a = 0.f;
    for (int c = 0; c < 128; ++c) a += wf1[t * 128 + c] * m[c];
    hid[t] = fmaxf(a + bf1[t], 0.f);
  }
  __syncthreads();
  {
    float a = 0.f;
    for (int r = 0; r < 32; ++r) a += wf2[t * 32 + r] * hid[r];
    a += bf2[t];
    sg[t] = 1.f / (1.f + expf(-a));
  }
  __syncthreads();
  for (int o = 0; o < 64; ++o) {
    float sc = w2g[o] * BN_INV;
    weffb[((size_t)b * 64 + o) * 128 + t] =
        f2bf((w2[o * 256 + t] * sg[t] + w2[o * 256 + 128 + t]) * sc);
  }
}

// ------ merged 1x1 MFMA: t1 bf16 (blk<256) | x2 (blk>=256) ------------------
__global__ __launch_bounds__(256) void k_t1x2(
    const u16* __restrict__ xhp, const u16* __restrict__ w1b,
    const float* __restrict__ w1bias, u16* __restrict__ t1b,
    const u16* __restrict__ pad, const u16* __restrict__ weffb,
    const float* __restrict__ x2bias, u16* __restrict__ xcat_pad) {
  int t = threadIdx.x;
  int wv = t >> 6, l = t & 63;
  int kg = l >> 4;
  if (blockIdx.x < 256) {
    int blk = blockIdx.x;
    int b = blk >> 6, y = blk & 63;
    int m0 = wv * 16;
    int xc = m0 + (l & 15);
    const u16* abase = xhp + ((size_t)(b * 66 + y + 1) * 66 + xc + 1) * 128 + kg * 8;
    const u16* bbase = w1b + (size_t)(l & 15) * 128 + kg * 8;
    f32x4 acc[4];
#pragma unroll
    for (int i = 0; i < 4; ++i) acc[i] = (f32x4){0.f, 0.f, 0.f, 0.f};
#pragma unroll
    for (int cc = 0; cc < 4; ++cc) {
      bf16x8 a = *(const bf16x8*)(abase + cc * 32);
#pragma unroll
      for (int nf = 0; nf < 4; ++nf) {
        bf16x8 bfr = *(const bf16x8*)(bbase + nf * 16 * 128 + cc * 32);
        acc[nf] = __builtin_amdgcn_mfma_f32_16x16x32_bf16(a, bfr, acc[nf], 0, 0, 0);
      }
    }
    int prow = m0 + (l >> 4) * 4;
    int ncol = l & 15;
    size_t pixb = ((size_t)b << 12) + ((size_t)y << 6);
#pragma unroll
    for (int nf = 0; nf < 4; ++nf) {
      int o = nf * 16 + ncol;
      float be = w1bias[o];
#pragma unroll
      for (int r = 0; r < 4; ++r)
        t1b[(pixb + prow + r) * 64 + o] = f2bf(fmaxf(acc[nf][r] + be, 0.f));
    }
    return;
  }
  int blk = blockIdx.x - 256;
  int b = blk >> 8, rr = blk & 255;
  int y = rr >> 1;
  int xseg = (rr & 1) << 6;
  int m0 = xseg + wv * 16;
  int xc = m0 + (l & 15);
  const u16* abase =
      pad + ((size_t)(b * 130 + y + 1) * 130 + xc + 1) * 256 + 128 + kg * 8;
  const u16* bbase = weffb + (size_t)b * 64 * 128 + (size_t)(l & 15) * 128 + kg * 8;
  f32x4 acc[4];
#pragma unroll
  for (int i = 0; i < 4; ++i) acc[i] = (f32x4){0.f, 0.f, 0.f, 0.f};
#pragma unroll
  for (int cc = 0; cc < 4; ++cc) {
    bf16x8 a = *(const bf16x8*)(abase + cc * 32);
#pragma unroll
    for (int nf = 0; nf < 4; ++nf) {
      bf16x8 bfr = *(const bf16x8*)(bbase + nf * 16 * 128 + cc * 32);
      acc[nf] = __builtin_amdgcn_mfma_f32_16x16x32_bf16(a, bfr, acc[nf], 0, 0, 0);
    }
  }
  int prow = m0 + (l >> 4) * 4;
  int ncol = l & 15;
  size_t rb = (size_t)(b * 130 + y + 1) * 130;
#pragma unroll
  for (int nf = 0; nf < 4; ++nf) {
    int o = nf * 16 + ncol;
    float be = x2bias[o];
#pragma unroll
    for (int r = 0; r < 4; ++r)
      xcat_pad[(rb + prow + r + 1) * 128 + 64 + o] =
          f2bf(fmaxf(acc[nf][r] + be, 0.f));
  }
}

// ------ bilinear up 64->128 of t1 (bf16,64ch) -> xcat_pad ch 0..63, 8ch/thr -
__global__ __launch_bounds__(256) void k_up64_pad(const u16* __restrict__ in,
                                                  u16* __restrict__ pad) {
  int t = threadIdx.x;
  int c0 = (t & 7) * 8;
  int px = t >> 3;                   // 32 px/block
  int g = blockIdx.x * 32 + px;      // B*16384
  int b = g >> 14, pp = g & 16383;
  int oy = pp >> 7, ox = pp & 127;
  const float S = 63.0f / 127.0f;
  float fy = oy * S, fx = ox * S;
  int y0 = (int)fy, x0 = (int)fx;
  int y1 = min(y0 + 1, 63), x1 = min(x0 + 1, 63);
  float wy = fy - y0, wx = fx - x0;
  const u16* base = in + (size_t)b * 4096 * 64 + c0;
  bf16x8 v00 = *(const bf16x8*)(base + ((y0 << 6) + x0) * 64);
  bf16x8 v01 = *(const bf16x8*)(base + ((y0 << 6) + x1) * 64);
  bf16x8 v10 = *(const bf16x8*)(base + ((y1 << 6) + x0) * 64);
  bf16x8 v11 = *(const bf16x8*)(base + ((y1 << 6) + x1) * 64);
  float f00[8], f01[8], f10[8], f11[8];
  unpack8(v00, f00); unpack8(v01, f01); unpack8(v10, f10); unpack8(v11, f11);
  ushort8 o;
#pragma unroll
  for (int j = 0; j < 8; ++j) {
    float top = f00[j] * (1.f - wx) + f01[j] * wx;
    float bot = f10[j] * (1.f - wx) + f11[j] * wx;
    o[j] = f2bf(top * (1.f - wy) + bot * wy);
  }
  *(ushort8*)(pad + ((size_t)(b * 130 + oy + 1) * 130 + ox + 1) * 128 + c0) = o;
}

// ------ bilinear up 64->128 of xr (bf16,128ch) -> xup bf16, 8ch/thread ------
__global__ __launch_bounds__(256) void k_up128_bf(
    const u16* __restrict__ in, u16* __restrict__ outb) {
  int t = threadIdx.x;
  int c0 = (t & 15) * 8;
  int px = t >> 4;
  int g = blockIdx.x * 16 + px;
  int b = g >> 14, pp = g & 16383;
  int oy = pp >> 7, ox = pp & 127;
  const float S = 63.0f / 127.0f;
  float fy = oy * S, fx = ox * S;
  int y0 = (int)fy, x0 = (int)fx;
  int y1 = min(y0 + 1, 63), x1 = min(x0 + 1, 63);
  float wy = fy - y0, wx = fx - x0;
  const u16* base = in + (size_t)b * 4096 * 128 + c0;
  bf16x8 v00 = *(const bf16x8*)(base + ((y0 << 6) + x0) * 128);
  bf16x8 v01 = *(const bf16x8*)(base + ((y0 << 6) + x1) * 128);
  bf16x8 v10 = *(const bf16x8*)(base + ((y1 << 6) + x0) * 128);
  bf16x8 v11 = *(const bf16x8*)(base + ((y1 << 6) + x1) * 128);
  float f00[8], f01[8], f10[8], f11[8];
  unpack8(v00, f00); unpack8(v01, f01); unpack8(v10, f10); unpack8(v11, f11);
  ushort8 o;
#pragma unroll
  for (int j = 0; j < 8; ++j) {
    float top = f00[j] * (1.f - wx) + f01[j] * wx;
    float bot = f10[j] * (1.f - wx) + f11[j] * wx;
    o[j] = f2bf(top * (1.f - wy) + bot * wy);
  }
  *(ushort8*)(outb + (size_t)g * 128 + c0) = o;
}

// ------ CARAFE reassembly (bf16 in) -> wo1-input pad ch 0..127, 8ch/thread --
__global__ __launch_bounds__(256) void k_carafe_bf(
    const u16* __restrict__ xup, const float* __restrict__ wk,
    u16* __restrict__ pad) {
  int t = threadIdx.x;
  int c0 = (t & 15) * 8;
  int px = t >> 4;
  int blk = (blockIdx.x & 7) * 512 + (blockIdx.x >> 3);
  int g = blk * 16 + px;
  int b = g >> 14, pp = g & 16383;
  int y = pp >> 7, x = pp & 127;
  __shared__ float wl[16][26];
  for (int i = t; i < 400; i += 256)
    wl[i / 25][i % 25] = wk[(size_t)(blk * 16 + i / 25) * 25 + (i % 25)];
  __syncthreads();
  float acc[8] = {0.f, 0.f, 0.f, 0.f, 0.f, 0.f, 0.f, 0.f};
  const u16* base = xup + ((size_t)b << 14) * 128 + c0;
#pragma unroll
  for (int i = 0; i < 5; ++i) {
    int row = y + 2 * i - 4;
    if ((unsigned)row >= 128u) continue;
#pragma unroll
    for (int jj = 0; jj < 5; ++jj) {
      int col = x + 2 * jj - 4;
      if ((unsigned)col >= 128u) continue;
      bf16x8 v = *(const bf16x8*)(base + (size_t)((row << 7) + col) * 128);
      float w = wl[px][i * 5 + jj];
      float f[8];
      unpack8(v, f);
#pragma unroll
      for (int k = 0; k < 8; ++k) acc[k] += w * f[k];
    }
  }
  ushort8 o;
#pragma unroll
  for (int k = 0; k < 8; ++k) o[k] = f2bf(acc[k]);
  *(ushort8*)(pad + ((size_t)(b * 130 + y + 1) * 130 + (x + 1)) * 256 + c0) = o;
}

extern "C" void kernel_launch(void* const* d_in, const int* in_sizes, int n_in,
                              void* d_out, int out_size, void* d_ws,
                              size_t ws_size, hipStream_t stream) {
  const float* x_h  = (const float*)d_in[0];
  const float* x_l  = (const float*)d_in[1];
  const float* wr   = (const float*)d_in[2];
  const float* wr_g = (const float*)d_in[3];
  const float* wr_b = (const float*)d_in[4];
  const float* w1   = (const float*)d_in[5];
  const float* w1_g = (const float*)d_in[6];
  const float* w1_b = (const float*)d_in[7];
  const float* w2   = (const float*)d_in[8];
  const float* w2_g = (const float*)d_in[9];
  const float* w2_b = (const float*)d_in[10];
  const float* we   = (const float*)d_in[11];
  const float* we_g = (const float*)d_in[12];
  const float* we_b = (const float*)d_in[13];
  const float* wf1  = (const float*)d_in[14];
  const float* bf1  = (const float*)d_in[15];
  const float* wf2  = (const float*)d_in[16];
  const float* bf2  = (const float*)d_in[17];
  const float* wo1  = (const float*)d_in[18];
  const float* wo1_g= (const float*)d_in[19];
  const float* wo1_b= (const float*)d_in[20];
  const float* wo2  = (const float*)d_in[21];
  const float* wo2_g= (const float*)d_in[22];
  const float* wo2_b= (const float*)d_in[23];
  float* out = (float*)d_out;

  float* ws = (float*)d_ws;
  u16* pad      = (u16*)ws;                  // [4][130][130][256] bf16
  u16* xcat_pad = (u16*)(ws + 8652800);      // [4][130][130][128] bf16
  u16* xup      = xcat_pad;                  // reuse after we conv
  float* wkb   = ws + 12979200;              // 1,638,400 f32
  u16* t1b = (u16*)(ws + 14617600);          // 2 MB bf16 (region 4 MB)
  u16* xr  = (u16*)(ws + 14617600);          // reuse after up64
  float* y1reg = ws + 15666176;              // 4,194,304 f32 region
  u16* xh_pad = (u16*)y1reg;                 // bf16 (early)
  float* gpart = ws + 19860480;              // 64*512 = 32,768 f32
  u16* weff_bf = (u16*)(gpart + 32768);      // 32,768 bf16
  float* tail  = gpart + 32768 + 16384;
  u16* wr_bf = (u16*)tail;                   // 147,456 bf16
  u16* we_bf = (u16*)(tail + 73728);         // 36,864 bf16
  u16* wo1bf = (u16*)(tail + 73728 + 18432);           // 294,912 bf16
  u16* wo2bf = (u16*)(tail + 73728 + 18432 + 147456);  // 16,384 bf16
  u16* w1bf  = (u16*)(tail + 73728 + 18432 + 147456 + 8192);  // 8,192 bf16

  hipMemsetAsync(gpart, 0, 32768 * sizeof(float), stream);
  k_setup<<<2024, 256, 0, stream>>>(pad, xcat_pad, xh_pad,
                                    wr, wr_g, we, we_g, wo1, wo1_g,
                                    wo2, wo2_g, w1, w1_g,
                                    wr_bf, we_bf, wo1bf, wo2bf, w1bf);

  k_stage_in<<<2048, 256, 0, stream>>>(x_h, x_l, xh_pad, pad, gpart);
  k_semlp<<<4, 128, 0, stream>>>(gpart, wf1, bf1, wf2, bf2, w2, w2_g, weff_bf);
  k_t1x2<<<1280, 256, 0, stream>>>(xh_pad, w1bf, w1_b, t1b,
                                   pad, weff_bf, w2_b, xcat_pad);
  k_up64_pad<<<2048, 256, 0, stream>>>(t1b, xcat_pad);         // ch 0..63

  // we: 512 thr, 8 waves 4Mx2N (proven config), fused softmax
  k_conv_mfma<130, 128, 32, 32, 128, 2, 512, 2><<<512, 512, 0, stream>>>(
      xcat_pad, we_bf, we_b, wkb);
  // wr: 512 thr, 2Mx4N (proven config)
  k_conv_mfma<66, 128, 128, 64, 64, 0, 512, 4><<<512, 512, 0, stream>>>(
      xh_pad, wr_bf, wr_b, xr);
  k_up128_bf<<<4096, 256, 0, stream>>>(xr, xup);
  k_carafe_bf<<<4096, 256, 0, stream>>>(xup, wkb, pad);
  // wo1 + fused wo2 epilogue (R13/R15 proven main loop)
  k_wo1wo2<<<512, 512, 0, stream>>>(pad, wo1bf, wo1_b, wo2bf, wo2_b, out);
}